// Round 1
// baseline (903.574 us; speedup 1.0000x reference)
//
#include <hip/hip_runtime.h>
#include <math.h>

#define NT 65536
#define EE 1048576
#define NB 128
#define KK 410          // kept nodes per graph = ceil(0.8*512)
#define N2 52480        // NB*KK
#define HH 128

// ---------------- device scratch (module globals; no d_ws dependence) --------
__device__ float g_h1[(size_t)NT * HH];
__device__ float g_h2[(size_t)NT * HH];
__device__ float g_agg[(size_t)NT * HH];
__device__ float g_hp[(size_t)N2 * HH];
__device__ float g_trel[NT];
__device__ float g_troot[NT];
__device__ float g_score[NT];
__device__ float g_gate[N2];
__device__ float g_xcat[NB * 512];
__device__ int g_deg1[NT];
__device__ int g_rows1[NT + 1];
__device__ int g_cur1[NT];
__device__ int g_csr1[EE];
__device__ int g_deg2[N2];
__device__ int g_rows2[N2 + 1];
__device__ int g_cur2[N2];
__device__ int g_csr2[EE];
__device__ int g_bsum[1024];
__device__ int g_bofs[1024];
__device__ int g_nmap[NT];
__device__ int g_perm[N2];

__device__ __forceinline__ float* fbuf(int id) {
    switch (id) {
        case 0: return g_h1;
        case 1: return g_h2;
        case 2: return g_agg;
        case 3: return g_hp;
    }
    return g_h1;
}
__device__ __forceinline__ int* ibuf(int id) {
    switch (id) {
        case 0: return g_deg1;
        case 1: return g_rows1;
        case 2: return g_cur1;
        case 3: return g_csr1;
        case 4: return g_deg2;
        case 5: return g_rows2;
        case 6: return g_cur2;
        case 7: return g_csr2;
    }
    return g_deg1;
}

// ---------------- CSR build ---------------------------------------------------
__global__ void k_zero(int id, int n) {
    int i = blockIdx.x * blockDim.x + threadIdx.x;
    if (i < n) ibuf(id)[i] = 0;
}

__global__ void k_deg1(const int* __restrict__ dst) {
    int e = blockIdx.x * blockDim.x + threadIdx.x;
    if (e < EE) atomicAdd(&g_deg1[dst[e]], 1);
}

__global__ void k_fill1(const int* __restrict__ src, const int* __restrict__ dst) {
    int e = blockIdx.x * blockDim.x + threadIdx.x;
    if (e < EE) {
        int d = dst[e];
        int p = atomicAdd(&g_cur1[d], 1);
        g_csr1[g_rows1[d] + p] = src[e];
    }
}

__global__ void k_deg2(const int* __restrict__ src, const int* __restrict__ dst) {
    int e = blockIdx.x * blockDim.x + threadIdx.x;
    if (e < EE) {
        int ns = g_nmap[src[e]], nd = g_nmap[dst[e]];
        if (ns >= 0 && nd >= 0) atomicAdd(&g_deg2[nd], 1);
    }
}

__global__ void k_fill2(const int* __restrict__ src, const int* __restrict__ dst) {
    int e = blockIdx.x * blockDim.x + threadIdx.x;
    if (e < EE) {
        int ns = g_nmap[src[e]], nd = g_nmap[dst[e]];
        if (ns >= 0 && nd >= 0) {
            int p = atomicAdd(&g_cur2[nd], 1);
            g_csr2[g_rows2[nd] + p] = ns;
        }
    }
}

// exclusive scan: 1024-elem blocks
__global__ __launch_bounds__(1024) void k_scan1(int inId, int outId, int n) {
    __shared__ int s[1024];
    const int* in = ibuf(inId);
    int* out = ibuf(outId);
    int i = blockIdx.x * 1024 + threadIdx.x;
    int v = (i < n) ? in[i] : 0;
    s[threadIdx.x] = v;
    __syncthreads();
    for (int off = 1; off < 1024; off <<= 1) {
        int t = (threadIdx.x >= (unsigned)off) ? s[threadIdx.x - off] : 0;
        __syncthreads();
        s[threadIdx.x] += t;
        __syncthreads();
    }
    if (i < n) out[i] = s[threadIdx.x] - v;
    if (threadIdx.x == 1023) g_bsum[blockIdx.x] = s[1023];
}

__global__ __launch_bounds__(1024) void k_scan2(int nb) {
    __shared__ int s[1024];
    int t = threadIdx.x;
    int v = (t < nb) ? g_bsum[t] : 0;
    s[t] = v;
    __syncthreads();
    for (int off = 1; off < 1024; off <<= 1) {
        int u = (t >= (unsigned)off) ? s[t - off] : 0;
        __syncthreads();
        s[t] += u;
        __syncthreads();
    }
    g_bofs[t] = s[t] - v;
}

__global__ __launch_bounds__(1024) void k_scan3(int rowsId, int degId, int n) {
    int* rows = ibuf(rowsId);
    const int* deg = ibuf(degId);
    int i = blockIdx.x * 1024 + threadIdx.x;
    if (i < n) {
        int r = rows[i] + g_bofs[blockIdx.x];
        rows[i] = r;
        if (i == n - 1) rows[n] = r + deg[i];
    }
}

// ---------------- mean aggregation over CSR (gather, no atomics) --------------
template <int D>
__global__ __launch_bounds__(256) void k_agg_mean(const float* __restrict__ hptr, int hId,
                                                  int rowsId, int csrId, int outId, int n) {
    const float* h = hptr ? hptr : fbuf(hId);
    const int* rows = ibuf(rowsId);
    const int* csr = ibuf(csrId);
    float* out = fbuf(outId);
    const int TPN = D / 4;          // threads per node (float4 per thread)
    const int npb = 256 / TPN;      // nodes per block
    int local = threadIdx.x / TPN;
    int t = threadIdx.x % TPN;
    int node = blockIdx.x * npb + local;
    if (node >= n) return;
    int r0 = rows[node], r1 = rows[node + 1];
    float4 acc = {0.f, 0.f, 0.f, 0.f};
    for (int e = r0; e < r1; e++) {
        int s = csr[e];
        float4 v = *(const float4*)&h[(size_t)s * D + t * 4];
        acc.x += v.x; acc.y += v.y; acc.z += v.z; acc.w += v.w;
    }
    int c = r1 - r0;
    float inv = 1.0f / (float)(c > 0 ? c : 1);
    acc.x *= inv; acc.y *= inv; acc.z *= inv; acc.w *= inv;
    *(float4*)&out[(size_t)node * D + t * 4] = acc;
}

// ---------------- fused dual-input matmul: out = relu(A@Wa + B@Wb + bias) -----
// out is [n,128]; 32-row tile per block; thread = 4 rows x 4 cols.
__global__ __launch_bounds__(256) void k_mm(const float* __restrict__ Aptr, int Aid, int KA,
                                            const float* __restrict__ Bptr, int Bid, int KB,
                                            const float* __restrict__ Wa, const float* __restrict__ Wb,
                                            const float* __restrict__ bias, int outId, int n) {
    const float* A = Aptr ? Aptr : fbuf(Aid);
    const float* Bv = Bptr ? Bptr : fbuf(Bid);
    float* out = fbuf(outId);
    __shared__ __align__(16) float a_t[32][32];   // [k][row]
    __shared__ __align__(16) float w_s[32 * 128]; // [k][col]
    float4* w4 = (float4*)w_s;
    int t = threadIdx.x;
    int row0 = blockIdx.x * 32;
    int cg = t & 31;   // col group (4 cols)
    int rg = t >> 5;   // row group (4 rows)
    int srow = t & 31; // staging: row
    int skg = t >> 5;  // staging: k-group of 4
    float4 acc0 = {0,0,0,0}, acc1 = {0,0,0,0}, acc2 = {0,0,0,0}, acc3 = {0,0,0,0};
    int K = KA + KB;
    for (int kc = 0; kc < K; kc += 32) {
        // stage A^T tile (32 rows x 32 k), transposed into LDS
        {
            const float* S;
            int kl, str;
            if (kc < KA) { S = A;  kl = kc + skg * 4;       str = KA; }
            else         { S = Bv; kl = kc - KA + skg * 4;  str = KB; }
            float4 v = *(const float4*)&S[(size_t)(row0 + srow) * str + kl];
            a_t[skg * 4 + 0][srow] = v.x;
            a_t[skg * 4 + 1][srow] = v.y;
            a_t[skg * 4 + 2][srow] = v.z;
            a_t[skg * 4 + 3][srow] = v.w;
        }
        // stage W tile (32 k x 128 cols), flat coalesced copy
        {
            const float* Wsrc;
            int kr0;
            if (kc < KA) { Wsrc = Wa; kr0 = kc; }
            else         { Wsrc = Wb; kr0 = kc - KA; }
            const float4* wg = (const float4*)(Wsrc + (size_t)kr0 * 128);
#pragma unroll
            for (int i = 0; i < 4; i++) w4[t + i * 256] = wg[t + i * 256];
        }
        __syncthreads();
#pragma unroll
        for (int kk = 0; kk < 32; kk++) {
            float4 av = *(const float4*)&a_t[kk][rg * 4];
            float4 wv = w4[kk * 32 + cg];
            acc0.x += av.x * wv.x; acc0.y += av.x * wv.y; acc0.z += av.x * wv.z; acc0.w += av.x * wv.w;
            acc1.x += av.y * wv.x; acc1.y += av.y * wv.y; acc1.z += av.y * wv.z; acc1.w += av.y * wv.w;
            acc2.x += av.z * wv.x; acc2.y += av.z * wv.y; acc2.z += av.z * wv.z; acc2.w += av.z * wv.w;
            acc3.x += av.w * wv.x; acc3.y += av.w * wv.y; acc3.z += av.w * wv.z; acc3.w += av.w * wv.w;
        }
        __syncthreads();
    }
    float4 bv = *(const float4*)&bias[cg * 4];
    int r = row0 + rg * 4;
    float4 o;
    o.x = fmaxf(acc0.x + bv.x, 0.f); o.y = fmaxf(acc0.y + bv.y, 0.f);
    o.z = fmaxf(acc0.z + bv.z, 0.f); o.w = fmaxf(acc0.w + bv.w, 0.f);
    *(float4*)&out[(size_t)(r + 0) * 128 + cg * 4] = o;
    o.x = fmaxf(acc1.x + bv.x, 0.f); o.y = fmaxf(acc1.y + bv.y, 0.f);
    o.z = fmaxf(acc1.z + bv.z, 0.f); o.w = fmaxf(acc1.w + bv.w, 0.f);
    *(float4*)&out[(size_t)(r + 1) * 128 + cg * 4] = o;
    o.x = fmaxf(acc2.x + bv.x, 0.f); o.y = fmaxf(acc2.y + bv.y, 0.f);
    o.z = fmaxf(acc2.z + bv.z, 0.f); o.w = fmaxf(acc2.w + bv.w, 0.f);
    *(float4*)&out[(size_t)(r + 2) * 128 + cg * 4] = o;
    o.x = fmaxf(acc3.x + bv.x, 0.f); o.y = fmaxf(acc3.y + bv.y, 0.f);
    o.z = fmaxf(acc3.z + bv.z, 0.f); o.w = fmaxf(acc3.w + bv.w, 0.f);
    *(float4*)&out[(size_t)(r + 3) * 128 + cg * 4] = o;
}

// ---------------- per-graph mean pool into xcat column block ------------------
__global__ __launch_bounds__(512) void k_pool(int hId, int npg, int col0) {
    const float* h = fbuf(hId);
    __shared__ float acc[4][128];
    int g = blockIdx.x, t = threadIdx.x;
    int sub = t >> 7, d = t & 127;
    float s = 0.f;
    for (int i = sub; i < npg; i += 4) s += h[(size_t)(g * npg + i) * 128 + d];
    acc[sub][d] = s;
    __syncthreads();
    if (t < 128) {
        float v = acc[0][t] + acc[1][t] + acc[2][t] + acc[3][t];
        g_xcat[g * 512 + col0 + t] = v / (float)npg;
    }
}

// ---------------- SAGPool scoring --------------------------------------------
__global__ __launch_bounds__(256) void k_score_dots(const float* __restrict__ pwr,
                                                    const float* __restrict__ pwt) {
    int wid = (blockIdx.x * 256 + threadIdx.x) >> 6;
    int lane = threadIdx.x & 63;
    if (wid >= NT) return;
    const float* row = g_h2 + (size_t)wid * 128;
    float h0 = row[lane], h1 = row[lane + 64];
    float a = h0 * pwr[lane] + h1 * pwr[lane + 64];
    float b = h0 * pwt[lane] + h1 * pwt[lane + 64];
    for (int off = 32; off > 0; off >>= 1) {
        a += __shfl_down(a, off);
        b += __shfl_down(b, off);
    }
    if (lane == 0) { g_trel[wid] = a; g_troot[wid] = b; }
}

__global__ void k_score_agg(const float* __restrict__ pb) {
    int i = blockIdx.x * blockDim.x + threadIdx.x;
    if (i >= NT) return;
    float s = 0.f;
    int r1 = g_rows1[i + 1];
    for (int e = g_rows1[i]; e < r1; e++) s += g_trel[g_csr1[e]];
    g_score[i] = s + g_troot[i] + pb[0];
}

// per-graph bitonic sort of 512 scores (desc value, asc index — matches lax.top_k)
__global__ __launch_bounds__(256) void k_topk() {
    __shared__ float sv[512];
    __shared__ int si[512];
    int g = blockIdx.x, t = threadIdx.x;
    for (int i = t; i < 512; i += 256) { sv[i] = g_score[g * 512 + i]; si[i] = i; }
    __syncthreads();
    for (int k = 2; k <= 512; k <<= 1) {
        for (int j = k >> 1; j > 0; j >>= 1) {
            for (int i = t; i < 512; i += 256) {
                int p = i ^ j;
                if (p > i) {
                    float va = sv[i], vb = sv[p];
                    int ia = si[i], ib = si[p];
                    bool aFirst = (va > vb) || (va == vb && ia < ib);
                    bool up = ((i & k) == 0);
                    if (up != aFirst) { sv[i] = vb; sv[p] = va; si[i] = ib; si[p] = ia; }
                }
            }
            __syncthreads();
        }
    }
    for (int r = t; r < 512; r += 256) {
        int old = g * 512 + si[r];
        if (r < KK) {
            int nn = g * KK + r;
            g_nmap[old] = nn;
            g_perm[nn] = old;
            g_gate[nn] = tanhf(sv[r]);
        } else {
            g_nmap[old] = -1;
        }
    }
}

__global__ void k_gate() {
    int tid = blockIdx.x * blockDim.x + threadIdx.x;
    if (tid >= N2 * 32) return;
    int nn = tid >> 5, c = tid & 31;
    int old = g_perm[nn];
    float gt = g_gate[nn];
    float4 v = *(const float4*)&g_h2[(size_t)old * 128 + c * 4];
    v.x *= gt; v.y *= gt; v.z *= gt; v.w *= gt;
    *(float4*)&g_hp[(size_t)nn * 128 + c * 4] = v;
}

// ---------------- MLP head + log_softmax -------------------------------------
__global__ __launch_bounds__(128) void k_head(const float* __restrict__ W1, const float* __restrict__ b1,
                                              const float* __restrict__ W2, const float* __restrict__ b2,
                                              float* __restrict__ out) {
    __shared__ float xr[512];
    __shared__ float r0[128], r1[128];
    int g = blockIdx.x, t = threadIdx.x;
    for (int i = t; i < 512; i += 128) xr[i] = g_xcat[g * 512 + i];
    __syncthreads();
    float acc = b1[t];
    for (int k = 0; k < 512; k++) acc += xr[k] * W1[k * 128 + t];
    acc = fmaxf(acc, 0.f);
    r0[t] = acc * W2[t * 2 + 0];
    r1[t] = acc * W2[t * 2 + 1];
    __syncthreads();
    for (int off = 64; off > 0; off >>= 1) {
        if (t < off) { r0[t] += r0[t + off]; r1[t] += r1[t + off]; }
        __syncthreads();
    }
    if (t == 0) {
        float z0 = r0[0] + b2[0], z1 = r1[0] + b2[1];
        float m = fmaxf(z0, z1);
        float l = m + logf(expf(z0 - m) + expf(z1 - m));
        out[g * 2 + 0] = z0 - l;
        out[g * 2 + 1] = z1 - l;
    }
}

// ---------------- launch ------------------------------------------------------
extern "C" void kernel_launch(void* const* d_in, const int* in_sizes, int n_in,
                              void* d_out, int out_size, void* d_ws, size_t ws_size,
                              hipStream_t stream) {
    const float* x = (const float*)d_in[0];
    const int* ei = (const int*)d_in[1];
    const int* src = ei;
    const int* dst = ei + EE;
    const float* W1r = (const float*)d_in[3];
    const float* W1o = (const float*)d_in[4];
    const float* b1 = (const float*)d_in[5];
    const float* Wcr = (const float*)d_in[6];
    const float* Wco = (const float*)d_in[7];
    const float* bc = (const float*)d_in[8];
    const float* pwr = (const float*)d_in[9];
    const float* pwt = (const float*)d_in[10];
    const float* pb = (const float*)d_in[11];
    const float* l1W = (const float*)d_in[12];
    const float* l1b = (const float*)d_in[13];
    const float* l2W = (const float*)d_in[14];
    const float* l2b = (const float*)d_in[15];
    float* out = (float*)d_out;

    // ---- CSR1 (full graph) ----
    k_zero<<<NT / 256, 256, 0, stream>>>(0, NT);
    k_deg1<<<EE / 256, 256, 0, stream>>>(dst);
    k_scan1<<<64, 1024, 0, stream>>>(0, 1, NT);
    k_scan2<<<1, 1024, 0, stream>>>(64);
    k_scan3<<<64, 1024, 0, stream>>>(1, 0, NT);
    k_zero<<<NT / 256, 256, 0, stream>>>(2, NT);
    k_fill1<<<EE / 256, 256, 0, stream>>>(src, dst);

    // ---- conv1: agg(x)[64] ; out = relu([agg|x] @ [W1r;W1o] + b1) -> h1 ----
    k_agg_mean<64><<<NT / 16, 256, 0, stream>>>(x, -1, 1, 3, 2, NT);
    k_mm<<<NT / 32, 256, 0, stream>>>(nullptr, 2, 64, x, -1, 64, W1r, W1o, b1, 0, NT);
    k_pool<<<NB, 512, 0, stream>>>(0, 512, 0);

    // ---- conv2 -> h2 ----
    k_agg_mean<128><<<NT / 8, 256, 0, stream>>>(nullptr, 0, 1, 3, 2, NT);
    k_mm<<<NT / 32, 256, 0, stream>>>(nullptr, 2, 128, nullptr, 0, 128, Wcr, Wco, bc, 1, NT);
    k_pool<<<NB, 512, 0, stream>>>(1, 512, 128);

    // ---- SAGPool: score (add-aggr), per-graph top-410, gate ----
    k_score_dots<<<NT * 64 / 256, 256, 0, stream>>>(pwr, pwt);
    k_score_agg<<<NT / 256, 256, 0, stream>>>(pb);
    k_topk<<<NB, 256, 0, stream>>>();
    k_gate<<<(N2 * 32) / 256, 256, 0, stream>>>();

    // ---- CSR2 (pooled graph, kept edges only) ----
    k_zero<<<(N2 + 255) / 256, 256, 0, stream>>>(4, N2);
    k_deg2<<<EE / 256, 256, 0, stream>>>(src, dst);
    k_scan1<<<52, 1024, 0, stream>>>(4, 5, N2);
    k_scan2<<<1, 1024, 0, stream>>>(52);
    k_scan3<<<52, 1024, 0, stream>>>(5, 4, N2);
    k_zero<<<(N2 + 255) / 256, 256, 0, stream>>>(6, N2);
    k_fill2<<<EE / 256, 256, 0, stream>>>(src, dst);

    // ---- conv3 (on hp) -> h1 ----
    k_agg_mean<128><<<N2 / 8, 256, 0, stream>>>(nullptr, 3, 5, 7, 2, N2);
    k_mm<<<N2 / 32, 256, 0, stream>>>(nullptr, 2, 128, nullptr, 3, 128,
                                      Wcr + 16384, Wco + 16384, bc + 128, 0, N2);
    k_pool<<<NB, 512, 0, stream>>>(0, 410, 256);

    // ---- conv4 -> h2 ----
    k_agg_mean<128><<<N2 / 8, 256, 0, stream>>>(nullptr, 0, 5, 7, 2, N2);
    k_mm<<<N2 / 32, 256, 0, stream>>>(nullptr, 2, 128, nullptr, 0, 128,
                                      Wcr + 32768, Wco + 32768, bc + 256, 1, N2);
    k_pool<<<NB, 512, 0, stream>>>(1, 410, 384);

    // ---- head ----
    k_head<<<NB, 128, 0, stream>>>(l1W, l1b, l2W, l2b, out);
}

// Round 2
// 740.793 us; speedup vs baseline: 1.2197x; 1.2197x over previous
//
#include <hip/hip_runtime.h>
#include <math.h>

#define NT 65536
#define EE 1048576
#define NB 128
#define KK 410          // kept nodes per graph = ceil(0.8*512)
#define N2 52480        // NB*KK
#define HH 128

typedef short bf16x8 __attribute__((ext_vector_type(8)));
typedef float f32x4 __attribute__((ext_vector_type(4)));

// ---------------- device scratch -------------------------------------------
__device__ unsigned short g_xb[(size_t)NT * 64];
__device__ unsigned short g_hb1[(size_t)NT * HH];
__device__ unsigned short g_hb2[(size_t)NT * HH];
__device__ unsigned short g_aggb[(size_t)NT * HH];
__device__ unsigned short g_hpb[(size_t)N2 * HH];
__device__ unsigned short g_aggb64[(size_t)NT * 64];
__device__ unsigned short g_wt1[128 * 128];
__device__ unsigned short g_wtc[3 * 128 * 256];
__device__ float g_trel[NT];
__device__ float g_troot[NT];
__device__ float g_score[NT];
__device__ float g_gate[N2];
__device__ float g_xcat[NB * 512];
__device__ int g_deg1[NT];
__device__ int g_rows1[NT + 1];
__device__ int g_cur1[NT];
__device__ int g_csr1[EE];
__device__ int g_deg2[N2];
__device__ int g_rows2[N2 + 1];
__device__ int g_cur2[N2];
__device__ int g_csr2[EE];
__device__ int g_bsum[1024];
__device__ int g_bofs[1024];
__device__ int g_nmap[NT];
__device__ int g_perm[N2];

__device__ __forceinline__ unsigned short* ubuf(int id) {
    switch (id) {
        case 0: return g_xb;
        case 1: return g_hb1;
        case 2: return g_hb2;
        case 3: return g_aggb;
        case 4: return g_hpb;
        case 5: return g_aggb64;
        case 6: return g_wt1;
        case 7: return g_wtc;
    }
    return g_xb;
}
__device__ __forceinline__ int* ibuf(int id) {
    switch (id) {
        case 0: return g_deg1;
        case 1: return g_rows1;
        case 2: return g_cur1;
        case 3: return g_csr1;
        case 4: return g_deg2;
        case 5: return g_rows2;
        case 6: return g_cur2;
        case 7: return g_csr2;
    }
    return g_deg1;
}

__device__ __forceinline__ float b2f(unsigned short u) {
    union { unsigned int i; float f; } v;
    v.i = ((unsigned int)u) << 16;
    return v.f;
}
__device__ __forceinline__ unsigned short f2b(float f) {
    unsigned int x = __float_as_uint(f);
    unsigned int r = x + 0x7fffu + ((x >> 16) & 1u);   // round-to-nearest-even
    return (unsigned short)(r >> 16);
}

// ---------------- weight prep: W_t[n][k] bf16 ------------------------------
__global__ void k_prep_w(const float* __restrict__ W1r, const float* __restrict__ W1o,
                         const float* __restrict__ Wcr, const float* __restrict__ Wco) {
    int tid = blockIdx.x * 256 + threadIdx.x;
    if (tid < 16384) {
        int k = tid & 127, n = tid >> 7;
        float v = (k < 64) ? W1r[k * 128 + n] : W1o[(k - 64) * 128 + n];
        g_wt1[n * 128 + k] = f2b(v);
    } else {
        int r = tid - 16384;
        if (r >= 3 * 32768) return;
        int l = r >> 15;
        int k = r & 255, n = (r >> 8) & 127;
        float v = (k < 128) ? Wcr[l * 16384 + k * 128 + n]
                            : Wco[l * 16384 + (k - 128) * 128 + n];
        g_wtc[l * 32768 + n * 256 + k] = f2b(v);
    }
}

// ---------------- x -> bf16 -------------------------------------------------
__global__ void k_x2b(const float* __restrict__ x) {
    int tid = blockIdx.x * 256 + threadIdx.x;   // one per 4 elems
    if (tid >= NT * 64 / 4) return;
    float4 v = *(const float4*)&x[(size_t)tid * 4];
    unsigned int lo = (unsigned int)f2b(v.x) | ((unsigned int)f2b(v.y) << 16);
    unsigned int hi = (unsigned int)f2b(v.z) | ((unsigned int)f2b(v.w) << 16);
    *(uint2*)&g_xb[(size_t)tid * 4] = make_uint2(lo, hi);
}

// ---------------- CSR build -------------------------------------------------
__global__ void k_zero(int id, int n) {
    int i = blockIdx.x * blockDim.x + threadIdx.x;
    if (i < n) ibuf(id)[i] = 0;
}

__global__ void k_deg1(const int* __restrict__ dst) {
    int e = blockIdx.x * blockDim.x + threadIdx.x;
    if (e < EE) atomicAdd(&g_deg1[dst[e]], 1);
}

__global__ void k_fill1(const int* __restrict__ src, const int* __restrict__ dst) {
    int e = blockIdx.x * blockDim.x + threadIdx.x;
    if (e < EE) {
        int d = dst[e];
        int p = atomicAdd(&g_cur1[d], 1);
        g_csr1[g_rows1[d] + p] = src[e];
    }
}

__global__ void k_deg2(const int* __restrict__ src, const int* __restrict__ dst) {
    int e = blockIdx.x * blockDim.x + threadIdx.x;
    if (e < EE) {
        int ns = g_nmap[src[e]], nd = g_nmap[dst[e]];
        if (ns >= 0 && nd >= 0) atomicAdd(&g_deg2[nd], 1);
    }
}

__global__ void k_fill2(const int* __restrict__ src, const int* __restrict__ dst) {
    int e = blockIdx.x * blockDim.x + threadIdx.x;
    if (e < EE) {
        int ns = g_nmap[src[e]], nd = g_nmap[dst[e]];
        if (ns >= 0 && nd >= 0) {
            int p = atomicAdd(&g_cur2[nd], 1);
            g_csr2[g_rows2[nd] + p] = ns;
        }
    }
}

__global__ __launch_bounds__(1024) void k_scan1(int inId, int outId, int n) {
    __shared__ int s[1024];
    const int* in = ibuf(inId);
    int* out = ibuf(outId);
    int i = blockIdx.x * 1024 + threadIdx.x;
    int v = (i < n) ? in[i] : 0;
    s[threadIdx.x] = v;
    __syncthreads();
    for (int off = 1; off < 1024; off <<= 1) {
        int t = (threadIdx.x >= (unsigned)off) ? s[threadIdx.x - off] : 0;
        __syncthreads();
        s[threadIdx.x] += t;
        __syncthreads();
    }
    if (i < n) out[i] = s[threadIdx.x] - v;
    if (threadIdx.x == 1023) g_bsum[blockIdx.x] = s[1023];
}

__global__ __launch_bounds__(1024) void k_scan2(int nb) {
    __shared__ int s[1024];
    int t = threadIdx.x;
    int v = (t < nb) ? g_bsum[t] : 0;
    s[t] = v;
    __syncthreads();
    for (int off = 1; off < 1024; off <<= 1) {
        int u = (t >= (unsigned)off) ? s[t - off] : 0;
        __syncthreads();
        s[t] += u;
        __syncthreads();
    }
    g_bofs[t] = s[t] - v;
}

__global__ __launch_bounds__(1024) void k_scan3(int rowsId, int degId, int n) {
    int* rows = ibuf(rowsId);
    const int* deg = ibuf(degId);
    int i = blockIdx.x * 1024 + threadIdx.x;
    if (i < n) {
        int r = rows[i] + g_bofs[blockIdx.x];
        rows[i] = r;
        if (i == n - 1) rows[n] = r + deg[i];
    }
}

// ---------------- mean aggregation (bf16 gather, fp32 accum, bf16 out) ------
template <int D>
__global__ __launch_bounds__(256) void k_agg_mean(int hId, int rowsId, int csrId,
                                                  int outId, int n) {
    const unsigned short* h = ubuf(hId);
    const int* rows = ibuf(rowsId);
    const int* csr = ibuf(csrId);
    unsigned short* out = ubuf(outId);
    const int TPN = D / 8;          // 8 bf16 = 16B per thread
    const int npb = 256 / TPN;
    int local = threadIdx.x / TPN;
    int t = threadIdx.x % TPN;
    int node = blockIdx.x * npb + local;
    if (node >= n) return;
    int r0 = rows[node], r1 = rows[node + 1];
    float acc[8];
#pragma unroll
    for (int i = 0; i < 8; i++) acc[i] = 0.f;
    for (int e = r0; e < r1; e++) {
        int s = csr[e];
        uint4 v = *(const uint4*)&h[(size_t)s * D + t * 8];
        acc[0] += b2f((unsigned short)(v.x & 0xffff));
        acc[1] += b2f((unsigned short)(v.x >> 16));
        acc[2] += b2f((unsigned short)(v.y & 0xffff));
        acc[3] += b2f((unsigned short)(v.y >> 16));
        acc[4] += b2f((unsigned short)(v.z & 0xffff));
        acc[5] += b2f((unsigned short)(v.z >> 16));
        acc[6] += b2f((unsigned short)(v.w & 0xffff));
        acc[7] += b2f((unsigned short)(v.w >> 16));
    }
    int c = r1 - r0;
    float inv = 1.0f / (float)(c > 0 ? c : 1);
    uint4 o;
    o.x = (unsigned int)f2b(acc[0] * inv) | ((unsigned int)f2b(acc[1] * inv) << 16);
    o.y = (unsigned int)f2b(acc[2] * inv) | ((unsigned int)f2b(acc[3] * inv) << 16);
    o.z = (unsigned int)f2b(acc[4] * inv) | ((unsigned int)f2b(acc[5] * inv) << 16);
    o.w = (unsigned int)f2b(acc[6] * inv) | ((unsigned int)f2b(acc[7] * inv) << 16);
    *(uint4*)&out[(size_t)node * D + t * 8] = o;
}

// ---------------- MFMA GEMM: out = relu([A|B] @ W + bias), N=128 ------------
// Wt layout: [n][K] bf16, element offset wOfs. Block 256 thr = 4 waves,
// 128 rows/block, wave = 2 row-tiles x 8 col-tiles of 16x16x32 MFMA.
template <int KA, int KB>
__global__ __launch_bounds__(256) void k_mm(int aId, int bId, int wId, int wOfs,
                                            const float* __restrict__ bias, int outId) {
    const unsigned short* Ap = ubuf(aId);
    const unsigned short* Bp = ubuf(bId);
    const unsigned short* Wt = ubuf(wId) + wOfs;
    unsigned short* out = ubuf(outId);
    const int K = KA + KB;
    int lane = threadIdx.x & 63;
    int w = threadIdx.x >> 6;
    int n16 = lane & 15, quad = lane >> 4;
    int rowbase = blockIdx.x * 128 + w * 32;
    f32x4 acc[2][8];
#pragma unroll
    for (int rt = 0; rt < 2; rt++)
#pragma unroll
        for (int ct = 0; ct < 8; ct++)
#pragma unroll
            for (int i = 0; i < 4; i++) acc[rt][ct][i] = 0.f;

#pragma unroll
    for (int ks = 0; ks < K / 32; ks++) {
        int k0 = ks * 32;
        const unsigned short* S;
        int kk, str;
        if (k0 < KA) { S = Ap; kk = k0; str = KA; }
        else         { S = Bp; kk = k0 - KA; str = KB; }
        bf16x8 a0 = *(const bf16x8*)&S[(size_t)(rowbase + n16) * str + kk + quad * 8];
        bf16x8 a1 = *(const bf16x8*)&S[(size_t)(rowbase + 16 + n16) * str + kk + quad * 8];
#pragma unroll
        for (int ct = 0; ct < 8; ct++) {
            bf16x8 b = *(const bf16x8*)&Wt[(size_t)(ct * 16 + n16) * K + k0 + quad * 8];
            acc[0][ct] = __builtin_amdgcn_mfma_f32_16x16x32_bf16(a0, b, acc[0][ct], 0, 0, 0);
            acc[1][ct] = __builtin_amdgcn_mfma_f32_16x16x32_bf16(a1, b, acc[1][ct], 0, 0, 0);
        }
    }
#pragma unroll
    for (int rt = 0; rt < 2; rt++)
#pragma unroll
        for (int ct = 0; ct < 8; ct++) {
            int c = ct * 16 + n16;
            float bv = bias[c];
#pragma unroll
            for (int i = 0; i < 4; i++) {
                int r = rowbase + rt * 16 + quad * 4 + i;
                out[(size_t)r * 128 + c] = f2b(fmaxf(acc[rt][ct][i] + bv, 0.f));
            }
        }
}

// ---------------- per-graph mean pool into xcat column block ----------------
__global__ __launch_bounds__(512) void k_pool(int hId, int npg, int col0) {
    const unsigned short* h = ubuf(hId);
    __shared__ float acc[4][128];
    int g = blockIdx.x, t = threadIdx.x;
    int sub = t >> 7, d = t & 127;
    float s = 0.f;
    for (int i = sub; i < npg; i += 4) s += b2f(h[(size_t)(g * npg + i) * 128 + d]);
    acc[sub][d] = s;
    __syncthreads();
    if (t < 128) {
        float v = acc[0][t] + acc[1][t] + acc[2][t] + acc[3][t];
        g_xcat[g * 512 + col0 + t] = v / (float)npg;
    }
}

// ---------------- SAGPool scoring -------------------------------------------
__global__ __launch_bounds__(256) void k_score_dots(const float* __restrict__ pwr,
                                                    const float* __restrict__ pwt) {
    int wid = (blockIdx.x * 256 + threadIdx.x) >> 6;
    int lane = threadIdx.x & 63;
    if (wid >= NT) return;
    const unsigned short* row = g_hb2 + (size_t)wid * 128;
    float h0 = b2f(row[lane]), h1 = b2f(row[lane + 64]);
    float a = h0 * pwr[lane] + h1 * pwr[lane + 64];
    float b = h0 * pwt[lane] + h1 * pwt[lane + 64];
    for (int off = 32; off > 0; off >>= 1) {
        a += __shfl_down(a, off);
        b += __shfl_down(b, off);
    }
    if (lane == 0) { g_trel[wid] = a; g_troot[wid] = b; }
}

__global__ void k_score_agg(const float* __restrict__ pb) {
    int i = blockIdx.x * blockDim.x + threadIdx.x;
    if (i >= NT) return;
    float s = 0.f;
    int r1 = g_rows1[i + 1];
    for (int e = g_rows1[i]; e < r1; e++) s += g_trel[g_csr1[e]];
    g_score[i] = s + g_troot[i] + pb[0];
}

// per-graph bitonic sort of 512 scores (desc value, asc index — matches lax.top_k)
__global__ __launch_bounds__(256) void k_topk() {
    __shared__ float sv[512];
    __shared__ int si[512];
    int g = blockIdx.x, t = threadIdx.x;
    for (int i = t; i < 512; i += 256) { sv[i] = g_score[g * 512 + i]; si[i] = i; }
    __syncthreads();
    for (int k = 2; k <= 512; k <<= 1) {
        for (int j = k >> 1; j > 0; j >>= 1) {
            for (int i = t; i < 512; i += 256) {
                int p = i ^ j;
                if (p > i) {
                    float va = sv[i], vb = sv[p];
                    int ia = si[i], ib = si[p];
                    bool aFirst = (va > vb) || (va == vb && ia < ib);
                    bool up = ((i & k) == 0);
                    if (up != aFirst) { sv[i] = vb; sv[p] = va; si[i] = ib; si[p] = ia; }
                }
            }
            __syncthreads();
        }
    }
    for (int r = t; r < 512; r += 256) {
        int old = g * 512 + si[r];
        if (r < KK) {
            int nn = g * KK + r;
            g_nmap[old] = nn;
            g_perm[nn] = old;
            g_gate[nn] = tanhf(sv[r]);
        } else {
            g_nmap[old] = -1;
        }
    }
}

__global__ void k_gate() {
    int tid = blockIdx.x * blockDim.x + threadIdx.x;
    if (tid >= N2 * 16) return;          // 8 bf16 per thread
    int nn = tid >> 4, c = tid & 15;
    int old = g_perm[nn];
    float gt = g_gate[nn];
    uint4 v = *(const uint4*)&g_hb2[(size_t)old * 128 + c * 8];
    uint4 o;
    o.x = (unsigned int)f2b(b2f((unsigned short)(v.x & 0xffff)) * gt) |
          ((unsigned int)f2b(b2f((unsigned short)(v.x >> 16)) * gt) << 16);
    o.y = (unsigned int)f2b(b2f((unsigned short)(v.y & 0xffff)) * gt) |
          ((unsigned int)f2b(b2f((unsigned short)(v.y >> 16)) * gt) << 16);
    o.z = (unsigned int)f2b(b2f((unsigned short)(v.z & 0xffff)) * gt) |
          ((unsigned int)f2b(b2f((unsigned short)(v.z >> 16)) * gt) << 16);
    o.w = (unsigned int)f2b(b2f((unsigned short)(v.w & 0xffff)) * gt) |
          ((unsigned int)f2b(b2f((unsigned short)(v.w >> 16)) * gt) << 16);
    *(uint4*)&g_hpb[(size_t)nn * 128 + c * 8] = o;
}

// ---------------- MLP head + log_softmax ------------------------------------
__global__ __launch_bounds__(128) void k_head(const float* __restrict__ W1, const float* __restrict__ b1,
                                              const float* __restrict__ W2, const float* __restrict__ b2,
                                              float* __restrict__ out) {
    __shared__ float xr[512];
    __shared__ float r0[128], r1[128];
    int g = blockIdx.x, t = threadIdx.x;
    for (int i = t; i < 512; i += 128) xr[i] = g_xcat[g * 512 + i];
    __syncthreads();
    float acc = b1[t];
    for (int k = 0; k < 512; k++) acc += xr[k] * W1[k * 128 + t];
    acc = fmaxf(acc, 0.f);
    r0[t] = acc * W2[t * 2 + 0];
    r1[t] = acc * W2[t * 2 + 1];
    __syncthreads();
    for (int off = 64; off > 0; off >>= 1) {
        if (t < off) { r0[t] += r0[t + off]; r1[t] += r1[t + off]; }
        __syncthreads();
    }
    if (t == 0) {
        float z0 = r0[0] + b2[0], z1 = r1[0] + b2[1];
        float m = fmaxf(z0, z1);
        float l = m + logf(expf(z0 - m) + expf(z1 - m));
        out[g * 2 + 0] = z0 - l;
        out[g * 2 + 1] = z1 - l;
    }
}

// ---------------- launch -----------------------------------------------------
extern "C" void kernel_launch(void* const* d_in, const int* in_sizes, int n_in,
                              void* d_out, int out_size, void* d_ws, size_t ws_size,
                              hipStream_t stream) {
    const float* x = (const float*)d_in[0];
    const int* ei = (const int*)d_in[1];
    const int* src = ei;
    const int* dst = ei + EE;
    const float* W1r = (const float*)d_in[3];
    const float* W1o = (const float*)d_in[4];
    const float* b1 = (const float*)d_in[5];
    const float* Wcr = (const float*)d_in[6];
    const float* Wco = (const float*)d_in[7];
    const float* bc = (const float*)d_in[8];
    const float* pwr = (const float*)d_in[9];
    const float* pwt = (const float*)d_in[10];
    const float* pb = (const float*)d_in[11];
    const float* l1W = (const float*)d_in[12];
    const float* l1b = (const float*)d_in[13];
    const float* l2W = (const float*)d_in[14];
    const float* l2b = (const float*)d_in[15];
    float* out = (float*)d_out;

    // ---- prep: weights transposed to bf16 [n][K], x to bf16 ----
    k_prep_w<<<448, 256, 0, stream>>>(W1r, W1o, Wcr, Wco);
    k_x2b<<<4096, 256, 0, stream>>>(x);

    // ---- CSR1 (full graph) ----
    k_zero<<<NT / 256, 256, 0, stream>>>(0, NT);
    k_deg1<<<EE / 256, 256, 0, stream>>>(dst);
    k_scan1<<<64, 1024, 0, stream>>>(0, 1, NT);
    k_scan2<<<1, 1024, 0, stream>>>(64);
    k_scan3<<<64, 1024, 0, stream>>>(1, 0, NT);
    k_zero<<<NT / 256, 256, 0, stream>>>(2, NT);
    k_fill1<<<EE / 256, 256, 0, stream>>>(src, dst);

    // ---- conv1: agg64(xb) ; hb1 = relu([agg|xb] @ wt1 + b1) ----
    k_agg_mean<64><<<NT / 32, 256, 0, stream>>>(0, 1, 3, 5, NT);
    k_mm<64, 64><<<NT / 128, 256, 0, stream>>>(5, 0, 6, 0, b1, 1);
    k_pool<<<NB, 512, 0, stream>>>(1, 512, 0);

    // ---- conv2 -> hb2 ----
    k_agg_mean<128><<<NT / 16, 256, 0, stream>>>(1, 1, 3, 3, NT);
    k_mm<128, 128><<<NT / 128, 256, 0, stream>>>(3, 1, 7, 0, bc, 2);
    k_pool<<<NB, 512, 0, stream>>>(2, 512, 128);

    // ---- SAGPool: score (add-aggr), per-graph top-410, gate ----
    k_score_dots<<<NT * 64 / 256, 256, 0, stream>>>(pwr, pwt);
    k_score_agg<<<NT / 256, 256, 0, stream>>>(pb);
    k_topk<<<NB, 256, 0, stream>>>();
    k_gate<<<(N2 * 16 + 255) / 256, 256, 0, stream>>>();

    // ---- CSR2 (pooled graph) ----
    k_zero<<<(N2 + 255) / 256, 256, 0, stream>>>(4, N2);
    k_deg2<<<EE / 256, 256, 0, stream>>>(src, dst);
    k_scan1<<<52, 1024, 0, stream>>>(4, 5, N2);
    k_scan2<<<1, 1024, 0, stream>>>(52);
    k_scan3<<<52, 1024, 0, stream>>>(5, 4, N2);
    k_zero<<<(N2 + 255) / 256, 256, 0, stream>>>(6, N2);
    k_fill2<<<EE / 256, 256, 0, stream>>>(src, dst);

    // ---- conv3 (on hpb) -> hb1 ----
    k_agg_mean<128><<<N2 / 16, 256, 0, stream>>>(4, 5, 7, 3, N2);
    k_mm<128, 128><<<N2 / 128, 256, 0, stream>>>(3, 4, 7, 32768, bc + 128, 1);
    k_pool<<<NB, 512, 0, stream>>>(1, 410, 256);

    // ---- conv4 -> hb2 ----
    k_agg_mean<128><<<N2 / 16, 256, 0, stream>>>(1, 5, 7, 3, N2);
    k_mm<128, 128><<<N2 / 128, 256, 0, stream>>>(3, 1, 7, 65536, bc + 256, 2);
    k_pool<<<NB, 512, 0, stream>>>(2, 410, 384);

    // ---- head ----
    k_head<<<NB, 128, 0, stream>>>(l1W, l1b, l2W, l2b, out);
}

// Round 3
// 664.125 us; speedup vs baseline: 1.3605x; 1.1154x over previous
//
#include <hip/hip_runtime.h>
#include <math.h>

#define NT 65536
#define EE 1048576
#define NB 128
#define KK 410          // kept nodes per graph = ceil(0.8*512)
#define N2 52480        // NB*KK
#define HH 128

typedef short bf16x8 __attribute__((ext_vector_type(8)));
typedef float f32x4 __attribute__((ext_vector_type(4)));

// ---------------- device scratch -------------------------------------------
__device__ unsigned short g_xb[(size_t)NT * 64];
__device__ unsigned short g_hb1[(size_t)NT * HH];
__device__ unsigned short g_hb2[(size_t)NT * HH];
__device__ unsigned short g_aggb[(size_t)NT * HH];
__device__ unsigned short g_hpb[(size_t)N2 * HH];
__device__ unsigned short g_aggb64[(size_t)NT * 64];
__device__ unsigned short g_wt1[128 * 128];
__device__ unsigned short g_wtc[3 * 128 * 256];
__device__ unsigned short g_csr1u[EE];   // src node id per edge, grouped by dst (2B)
__device__ unsigned short g_csr2u[EE];
__device__ unsigned short g_slot[EE];    // slot within dst's edge list (from deg pass)
__device__ unsigned short g_es2[EE];     // remapped src (phase 2)
__device__ unsigned short g_ed2[EE];     // remapped dst (phase 2)
__device__ unsigned int g_flag1[64];
__device__ unsigned int g_flag2[64];
__device__ float g_trel[NT];
__device__ float g_troot[NT];
__device__ float g_score[NT];
__device__ float g_gate[N2];
__device__ float g_xcat[NB * 512];
__device__ int g_deg1[NT];
__device__ int g_rows1[NT + 1];
__device__ int g_deg2[N2];
__device__ int g_rows2[N2 + 1];
__device__ int g_nmap[NT];
__device__ int g_perm[N2];

__device__ __forceinline__ unsigned short* ubuf(int id) {
    switch (id) {
        case 0: return g_xb;
        case 1: return g_hb1;
        case 2: return g_hb2;
        case 3: return g_aggb;
        case 4: return g_hpb;
        case 5: return g_aggb64;
        case 6: return g_wt1;
        case 7: return g_wtc;
        case 8: return g_csr1u;
        case 9: return g_csr2u;
    }
    return g_xb;
}
__device__ __forceinline__ int* ibuf(int id) {
    switch (id) {
        case 0: return g_deg1;
        case 1: return g_rows1;
        case 4: return g_deg2;
        case 5: return g_rows2;
    }
    return g_deg1;
}

__device__ __forceinline__ float b2f(unsigned short u) {
    union { unsigned int i; float f; } v;
    v.i = ((unsigned int)u) << 16;
    return v.f;
}
__device__ __forceinline__ unsigned short f2b(float f) {
    unsigned int x = __float_as_uint(f);
    unsigned int r = x + 0x7fffu + ((x >> 16) & 1u);   // round-to-nearest-even
    return (unsigned short)(r >> 16);
}

// ---------------- weight prep (+ zero deg1/flag1) ---------------------------
// tids: [0,16384) wt1 | [16384,114688) wtc | [114688,180224) deg1=0 | +64 flag1=0
__global__ void k_prep_w(const float* __restrict__ W1r, const float* __restrict__ W1o,
                         const float* __restrict__ Wcr, const float* __restrict__ Wco) {
    int tid = blockIdx.x * 256 + threadIdx.x;
    if (tid < 16384) {
        int k = tid & 127, n = tid >> 7;
        float v = (k < 64) ? W1r[k * 128 + n] : W1o[(k - 64) * 128 + n];
        g_wt1[n * 128 + k] = f2b(v);
    } else if (tid < 114688) {
        int r = tid - 16384;
        int l = r >> 15;
        int k = r & 255, n = (r >> 8) & 127;
        float v = (k < 128) ? Wcr[l * 16384 + k * 128 + n]
                            : Wco[l * 16384 + (k - 128) * 128 + n];
        g_wtc[l * 32768 + n * 256 + k] = f2b(v);
    } else if (tid < 180224) {
        g_deg1[tid - 114688] = 0;
    } else if (tid < 180288) {
        g_flag1[tid - 180224] = 0;
    }
}

// ---------------- x -> bf16 -------------------------------------------------
__global__ void k_x2b(const float* __restrict__ x) {
    int tid = blockIdx.x * 256 + threadIdx.x;   // one per 4 elems
    if (tid >= NT * 64 / 4) return;
    float4 v = *(const float4*)&x[(size_t)tid * 4];
    unsigned int lo = (unsigned int)f2b(v.x) | ((unsigned int)f2b(v.y) << 16);
    unsigned int hi = (unsigned int)f2b(v.z) | ((unsigned int)f2b(v.w) << 16);
    *(uint2*)&g_xb[(size_t)tid * 4] = make_uint2(lo, hi);
}

// ---------------- CSR build: deg pass records slot, fill has no atomics -----
__global__ __launch_bounds__(256) void k_deg1(const int* __restrict__ dst) {
    int e0 = (blockIdx.x * 256 + threadIdx.x) * 4;
    if (e0 >= EE) return;
    int4 d = *(const int4*)&dst[e0];
    ushort4 sl;
    sl.x = (unsigned short)atomicAdd(&g_deg1[d.x], 1);
    sl.y = (unsigned short)atomicAdd(&g_deg1[d.y], 1);
    sl.z = (unsigned short)atomicAdd(&g_deg1[d.z], 1);
    sl.w = (unsigned short)atomicAdd(&g_deg1[d.w], 1);
    *(ushort4*)&g_slot[e0] = sl;
}

__global__ __launch_bounds__(256) void k_fill1(const int* __restrict__ src,
                                               const int* __restrict__ dst) {
    int e0 = (blockIdx.x * 256 + threadIdx.x) * 4;
    if (e0 >= EE) return;
    int4 s = *(const int4*)&src[e0];
    int4 d = *(const int4*)&dst[e0];
    ushort4 sl = *(const ushort4*)&g_slot[e0];
    g_csr1u[g_rows1[d.x] + sl.x] = (unsigned short)s.x;
    g_csr1u[g_rows1[d.y] + sl.y] = (unsigned short)s.y;
    g_csr1u[g_rows1[d.z] + sl.z] = (unsigned short)s.z;
    g_csr1u[g_rows1[d.w] + sl.w] = (unsigned short)s.w;
}

__global__ __launch_bounds__(256) void k_deg2(const int* __restrict__ src,
                                              const int* __restrict__ dst) {
    int e0 = (blockIdx.x * 256 + threadIdx.x) * 4;
    if (e0 >= EE) return;
    int4 s = *(const int4*)&src[e0];
    int4 d = *(const int4*)&dst[e0];
    ushort4 sl, es, ed;
#define DO_EDGE(comp)                                                         \
    {                                                                         \
        int ns = g_nmap[s.comp], nd = g_nmap[d.comp];                         \
        if (ns >= 0 && nd >= 0) {                                             \
            sl.comp = (unsigned short)atomicAdd(&g_deg2[nd], 1);              \
            es.comp = (unsigned short)ns;                                     \
            ed.comp = (unsigned short)nd;                                     \
        } else {                                                              \
            sl.comp = 0xFFFFu; es.comp = 0; ed.comp = 0;                      \
        }                                                                     \
    }
    DO_EDGE(x) DO_EDGE(y) DO_EDGE(z) DO_EDGE(w)
#undef DO_EDGE
    *(ushort4*)&g_slot[e0] = sl;
    *(ushort4*)&g_es2[e0] = es;
    *(ushort4*)&g_ed2[e0] = ed;
}

__global__ __launch_bounds__(256) void k_fill2() {
    int e0 = (blockIdx.x * 256 + threadIdx.x) * 4;
    if (e0 >= EE) return;
    ushort4 sl = *(const ushort4*)&g_slot[e0];
    ushort4 es = *(const ushort4*)&g_es2[e0];
    ushort4 ed = *(const ushort4*)&g_ed2[e0];
    if (sl.x != 0xFFFFu) g_csr2u[g_rows2[ed.x] + sl.x] = es.x;
    if (sl.y != 0xFFFFu) g_csr2u[g_rows2[ed.y] + sl.y] = es.y;
    if (sl.z != 0xFFFFu) g_csr2u[g_rows2[ed.z] + sl.z] = es.z;
    if (sl.w != 0xFFFFu) g_csr2u[g_rows2[ed.w] + sl.w] = es.w;
}

// ---------------- single-pass exclusive scan (chained lookback) -------------
__global__ __launch_bounds__(1024) void k_scan(int degId, int rowsId, int n, int flagSel) {
    __shared__ int s[1024];
    __shared__ unsigned int sprefix;
    unsigned int* flag = flagSel ? g_flag2 : g_flag1;
    const int* deg = ibuf(degId);
    int* rows = ibuf(rowsId);
    int tid = threadIdx.x;
    int i = blockIdx.x * 1024 + tid;
    int v = (i < n) ? deg[i] : 0;
    s[tid] = v;
    __syncthreads();
    for (int off = 1; off < 1024; off <<= 1) {
        int t2 = (tid >= off) ? s[tid - off] : 0;
        __syncthreads();
        s[tid] += t2;
        __syncthreads();
    }
    if (tid == 1023) {
        unsigned int p = 0;
        if (blockIdx.x > 0) {
            unsigned int f;
            while ((f = atomicAdd(&flag[blockIdx.x - 1], 0u)) == 0u) {}
            p = f - 1;
        }
        atomicExch(&flag[blockIdx.x], p + (unsigned int)s[1023] + 1u);
        sprefix = p;
    }
    __syncthreads();
    int base = (int)sprefix;
    if (i < n) rows[i] = base + s[tid] - v;
    if (i == n - 1) rows[n] = base + s[tid];
}

// ---------------- mean aggregation (unroll-4 gather for MLP) ----------------
template <int D>
__global__ __launch_bounds__(256) void k_agg_mean(int hId, int rowsId, int csrId,
                                                  int outId, int n) {
    const unsigned short* h = ubuf(hId);
    const int* rows = ibuf(rowsId);
    const unsigned short* csr = ubuf(csrId);
    unsigned short* out = ubuf(outId);
    const int TPN = D / 8;          // 8 bf16 = 16B per thread
    const int npb = 256 / TPN;
    int local = threadIdx.x / TPN;
    int t = threadIdx.x % TPN;
    int node = blockIdx.x * npb + local;
    if (node >= n) return;
    int r0 = rows[node], r1 = rows[node + 1];
    float acc[8];
#pragma unroll
    for (int i = 0; i < 8; i++) acc[i] = 0.f;
    const unsigned short* ht = h + t * 8;
#define ACCV(v)                                                  \
    acc[0] += b2f((unsigned short)(v.x & 0xffff));               \
    acc[1] += b2f((unsigned short)(v.x >> 16));                  \
    acc[2] += b2f((unsigned short)(v.y & 0xffff));               \
    acc[3] += b2f((unsigned short)(v.y >> 16));                  \
    acc[4] += b2f((unsigned short)(v.z & 0xffff));               \
    acc[5] += b2f((unsigned short)(v.z >> 16));                  \
    acc[6] += b2f((unsigned short)(v.w & 0xffff));               \
    acc[7] += b2f((unsigned short)(v.w >> 16));
    int e = r0;
    for (; e + 4 <= r1; e += 4) {
        int i0 = csr[e], i1 = csr[e + 1], i2 = csr[e + 2], i3 = csr[e + 3];
        uint4 v0 = *(const uint4*)&ht[(size_t)i0 * D];
        uint4 v1 = *(const uint4*)&ht[(size_t)i1 * D];
        uint4 v2 = *(const uint4*)&ht[(size_t)i2 * D];
        uint4 v3 = *(const uint4*)&ht[(size_t)i3 * D];
        ACCV(v0) ACCV(v1) ACCV(v2) ACCV(v3)
    }
    for (; e < r1; e++) {
        int i0 = csr[e];
        uint4 v0 = *(const uint4*)&ht[(size_t)i0 * D];
        ACCV(v0)
    }
#undef ACCV
    int c = r1 - r0;
    float inv = 1.0f / (float)(c > 0 ? c : 1);
    uint4 o;
    o.x = (unsigned int)f2b(acc[0] * inv) | ((unsigned int)f2b(acc[1] * inv) << 16);
    o.y = (unsigned int)f2b(acc[2] * inv) | ((unsigned int)f2b(acc[3] * inv) << 16);
    o.z = (unsigned int)f2b(acc[4] * inv) | ((unsigned int)f2b(acc[5] * inv) << 16);
    o.w = (unsigned int)f2b(acc[6] * inv) | ((unsigned int)f2b(acc[7] * inv) << 16);
    *(uint4*)&out[(size_t)node * D + t * 8] = o;
}

// ---------------- MFMA GEMM: out = relu([A|B] @ W + bias), N=128 ------------
template <int KA, int KB>
__global__ __launch_bounds__(256) void k_mm(int aId, int bId, int wId, int wOfs,
                                            const float* __restrict__ bias, int outId) {
    const unsigned short* Ap = ubuf(aId);
    const unsigned short* Bp = ubuf(bId);
    const unsigned short* Wt = ubuf(wId) + wOfs;
    unsigned short* out = ubuf(outId);
    const int K = KA + KB;
    int lane = threadIdx.x & 63;
    int w = threadIdx.x >> 6;
    int n16 = lane & 15, quad = lane >> 4;
    int rowbase = blockIdx.x * 128 + w * 32;
    f32x4 acc[2][8];
#pragma unroll
    for (int rt = 0; rt < 2; rt++)
#pragma unroll
        for (int ct = 0; ct < 8; ct++)
#pragma unroll
            for (int i = 0; i < 4; i++) acc[rt][ct][i] = 0.f;

#pragma unroll
    for (int ks = 0; ks < K / 32; ks++) {
        int k0 = ks * 32;
        const unsigned short* S;
        int kk, str;
        if (k0 < KA) { S = Ap; kk = k0; str = KA; }
        else         { S = Bp; kk = k0 - KA; str = KB; }
        bf16x8 a0 = *(const bf16x8*)&S[(size_t)(rowbase + n16) * str + kk + quad * 8];
        bf16x8 a1 = *(const bf16x8*)&S[(size_t)(rowbase + 16 + n16) * str + kk + quad * 8];
#pragma unroll
        for (int ct = 0; ct < 8; ct++) {
            bf16x8 b = *(const bf16x8*)&Wt[(size_t)(ct * 16 + n16) * K + k0 + quad * 8];
            acc[0][ct] = __builtin_amdgcn_mfma_f32_16x16x32_bf16(a0, b, acc[0][ct], 0, 0, 0);
            acc[1][ct] = __builtin_amdgcn_mfma_f32_16x16x32_bf16(a1, b, acc[1][ct], 0, 0, 0);
        }
    }
#pragma unroll
    for (int rt = 0; rt < 2; rt++)
#pragma unroll
        for (int ct = 0; ct < 8; ct++) {
            int c = ct * 16 + n16;
            float bv = bias[c];
#pragma unroll
            for (int i = 0; i < 4; i++) {
                int r = rowbase + rt * 16 + quad * 4 + i;
                out[(size_t)r * 128 + c] = f2b(fmaxf(acc[rt][ct][i] + bv, 0.f));
            }
        }
}

// ---------------- per-graph mean pool into xcat column block ----------------
__global__ __launch_bounds__(512) void k_pool(int hId, int npg, int col0) {
    const unsigned short* h = ubuf(hId);
    __shared__ float acc[4][128];
    int g = blockIdx.x, t = threadIdx.x;
    int sub = t >> 7, d = t & 127;
    float s = 0.f;
    for (int i = sub; i < npg; i += 4) s += b2f(h[(size_t)(g * npg + i) * 128 + d]);
    acc[sub][d] = s;
    __syncthreads();
    if (t < 128) {
        float v = acc[0][t] + acc[1][t] + acc[2][t] + acc[3][t];
        g_xcat[g * 512 + col0 + t] = v / (float)npg;
    }
}

// ---------------- SAGPool scoring -------------------------------------------
__global__ __launch_bounds__(256) void k_score_dots(const float* __restrict__ pwr,
                                                    const float* __restrict__ pwt) {
    int wid = (blockIdx.x * 256 + threadIdx.x) >> 6;
    int lane = threadIdx.x & 63;
    if (wid >= NT) return;
    const unsigned short* row = g_hb2 + (size_t)wid * 128;
    float h0 = b2f(row[lane]), h1 = b2f(row[lane + 64]);
    float a = h0 * pwr[lane] + h1 * pwr[lane + 64];
    float b = h0 * pwt[lane] + h1 * pwt[lane + 64];
    for (int off = 32; off > 0; off >>= 1) {
        a += __shfl_down(a, off);
        b += __shfl_down(b, off);
    }
    if (lane == 0) { g_trel[wid] = a; g_troot[wid] = b; }
}

__global__ void k_score_agg(const float* __restrict__ pb) {
    int i = blockIdx.x * blockDim.x + threadIdx.x;
    if (i >= NT) return;
    int r0 = g_rows1[i], r1 = g_rows1[i + 1];
    float s = 0.f;
    int e = r0;
    for (; e + 4 <= r1; e += 4) {
        float s0 = g_trel[g_csr1u[e]];
        float s1 = g_trel[g_csr1u[e + 1]];
        float s2 = g_trel[g_csr1u[e + 2]];
        float s3 = g_trel[g_csr1u[e + 3]];
        s += (s0 + s1) + (s2 + s3);
    }
    for (; e < r1; e++) s += g_trel[g_csr1u[e]];
    g_score[i] = s + g_troot[i] + pb[0];
}

// per-graph bitonic sort of 512 scores (desc value, asc index — matches lax.top_k)
__global__ __launch_bounds__(256) void k_topk() {
    __shared__ float sv[512];
    __shared__ int si[512];
    int g = blockIdx.x, t = threadIdx.x;
    for (int i = t; i < 512; i += 256) { sv[i] = g_score[g * 512 + i]; si[i] = i; }
    __syncthreads();
    for (int k = 2; k <= 512; k <<= 1) {
        for (int j = k >> 1; j > 0; j >>= 1) {
            for (int i = t; i < 512; i += 256) {
                int p = i ^ j;
                if (p > i) {
                    float va = sv[i], vb = sv[p];
                    int ia = si[i], ib = si[p];
                    bool aFirst = (va > vb) || (va == vb && ia < ib);
                    bool up = ((i & k) == 0);
                    if (up != aFirst) { sv[i] = vb; sv[p] = va; si[i] = ib; si[p] = ia; }
                }
            }
            __syncthreads();
        }
    }
    for (int r = t; r < 512; r += 256) {
        int old = g * 512 + si[r];
        if (r < KK) {
            int nn = g * KK + r;
            g_nmap[old] = nn;
            g_perm[nn] = old;
            g_gate[nn] = tanhf(sv[r]);
        } else {
            g_nmap[old] = -1;
        }
    }
}

// gate kept nodes (+ zero deg2/flag2 for phase-2 CSR build)
__global__ void k_gate() {
    int tid = blockIdx.x * blockDim.x + threadIdx.x;
    if (tid < N2) g_deg2[tid] = 0;
    else if (tid < N2 + 64) g_flag2[tid - N2] = 0;
    if (tid >= N2 * 16) return;          // 8 bf16 per thread
    int nn = tid >> 4, c = tid & 15;
    int old = g_perm[nn];
    float gt = g_gate[nn];
    uint4 v = *(const uint4*)&g_hb2[(size_t)old * 128 + c * 8];
    uint4 o;
    o.x = (unsigned int)f2b(b2f((unsigned short)(v.x & 0xffff)) * gt) |
          ((unsigned int)f2b(b2f((unsigned short)(v.x >> 16)) * gt) << 16);
    o.y = (unsigned int)f2b(b2f((unsigned short)(v.y & 0xffff)) * gt) |
          ((unsigned int)f2b(b2f((unsigned short)(v.y >> 16)) * gt) << 16);
    o.z = (unsigned int)f2b(b2f((unsigned short)(v.z & 0xffff)) * gt) |
          ((unsigned int)f2b(b2f((unsigned short)(v.z >> 16)) * gt) << 16);
    o.w = (unsigned int)f2b(b2f((unsigned short)(v.w & 0xffff)) * gt) |
          ((unsigned int)f2b(b2f((unsigned short)(v.w >> 16)) * gt) << 16);
    *(uint4*)&g_hpb[(size_t)nn * 128 + c * 8] = o;
}

// ---------------- MLP head + log_softmax ------------------------------------
__global__ __launch_bounds__(128) void k_head(const float* __restrict__ W1, const float* __restrict__ b1,
                                              const float* __restrict__ W2, const float* __restrict__ b2,
                                              float* __restrict__ out) {
    __shared__ float xr[512];
    __shared__ float r0[128], r1[128];
    int g = blockIdx.x, t = threadIdx.x;
    for (int i = t; i < 512; i += 128) xr[i] = g_xcat[g * 512 + i];
    __syncthreads();
    float acc = b1[t];
    for (int k = 0; k < 512; k++) acc += xr[k] * W1[k * 128 + t];
    acc = fmaxf(acc, 0.f);
    r0[t] = acc * W2[t * 2 + 0];
    r1[t] = acc * W2[t * 2 + 1];
    __syncthreads();
    for (int off = 64; off > 0; off >>= 1) {
        if (t < off) { r0[t] += r0[t + off]; r1[t] += r1[t + off]; }
        __syncthreads();
    }
    if (t == 0) {
        float z0 = r0[0] + b2[0], z1 = r1[0] + b2[1];
        float m = fmaxf(z0, z1);
        float l = m + logf(expf(z0 - m) + expf(z1 - m));
        out[g * 2 + 0] = z0 - l;
        out[g * 2 + 1] = z1 - l;
    }
}

// ---------------- launch -----------------------------------------------------
extern "C" void kernel_launch(void* const* d_in, const int* in_sizes, int n_in,
                              void* d_out, int out_size, void* d_ws, size_t ws_size,
                              hipStream_t stream) {
    const float* x = (const float*)d_in[0];
    const int* ei = (const int*)d_in[1];
    const int* src = ei;
    const int* dst = ei + EE;
    const float* W1r = (const float*)d_in[3];
    const float* W1o = (const float*)d_in[4];
    const float* b1 = (const float*)d_in[5];
    const float* Wcr = (const float*)d_in[6];
    const float* Wco = (const float*)d_in[7];
    const float* bc = (const float*)d_in[8];
    const float* pwr = (const float*)d_in[9];
    const float* pwt = (const float*)d_in[10];
    const float* pb = (const float*)d_in[11];
    const float* l1W = (const float*)d_in[12];
    const float* l1b = (const float*)d_in[13];
    const float* l2W = (const float*)d_in[14];
    const float* l2b = (const float*)d_in[15];
    float* out = (float*)d_out;

    // ---- prep: weights -> bf16 [n][K], x -> bf16, zero deg1/flag1 ----
    k_prep_w<<<705, 256, 0, stream>>>(W1r, W1o, Wcr, Wco);
    k_x2b<<<4096, 256, 0, stream>>>(x);

    // ---- CSR1 (full graph): deg+slot, scan, atomic-free fill ----
    k_deg1<<<1024, 256, 0, stream>>>(dst);
    k_scan<<<64, 1024, 0, stream>>>(0, 1, NT, 0);
    k_fill1<<<1024, 256, 0, stream>>>(src, dst);

    // ---- conv1: agg64(xb) ; hb1 = relu([agg|xb] @ wt1 + b1) ----
    k_agg_mean<64><<<NT / 32, 256, 0, stream>>>(0, 1, 8, 5, NT);
    k_mm<64, 64><<<NT / 128, 256, 0, stream>>>(5, 0, 6, 0, b1, 1);
    k_pool<<<NB, 512, 0, stream>>>(1, 512, 0);

    // ---- conv2 -> hb2 ----
    k_agg_mean<128><<<NT / 16, 256, 0, stream>>>(1, 1, 8, 3, NT);
    k_mm<128, 128><<<NT / 128, 256, 0, stream>>>(3, 1, 7, 0, bc, 2);
    k_pool<<<NB, 512, 0, stream>>>(2, 512, 128);

    // ---- SAGPool: score (add-aggr), per-graph top-410, gate ----
    k_score_dots<<<NT * 64 / 256, 256, 0, stream>>>(pwr, pwt);
    k_score_agg<<<NT / 256, 256, 0, stream>>>(pb);
    k_topk<<<NB, 256, 0, stream>>>();
    k_gate<<<(N2 * 16 + 255) / 256, 256, 0, stream>>>();

    // ---- CSR2 (pooled graph) ----
    k_deg2<<<1024, 256, 0, stream>>>(src, dst);
    k_scan<<<52, 1024, 0, stream>>>(4, 5, N2, 1);
    k_fill2<<<1024, 256, 0, stream>>>();

    // ---- conv3 (on hpb) -> hb1 ----
    k_agg_mean<128><<<N2 / 16, 256, 0, stream>>>(4, 5, 9, 3, N2);
    k_mm<128, 128><<<N2 / 128, 256, 0, stream>>>(3, 4, 7, 32768, bc + 128, 1);
    k_pool<<<NB, 512, 0, stream>>>(1, 410, 256);

    // ---- conv4 -> hb2 ----
    k_agg_mean<128><<<N2 / 16, 256, 0, stream>>>(1, 5, 9, 3, N2);
    k_mm<128, 128><<<N2 / 128, 256, 0, stream>>>(3, 1, 7, 65536, bc + 256, 2);
    k_pool<<<NB, 512, 0, stream>>>(2, 410, 384);

    // ---- head ----
    k_head<<<NB, 128, 0, stream>>>(l1W, l1b, l2W, l2b, out);
}

// Round 4
// 643.320 us; speedup vs baseline: 1.4045x; 1.0323x over previous
//
#include <hip/hip_runtime.h>
#include <math.h>

#define NT 65536
#define EE 1048576
#define NB 128
#define KK 410          // kept nodes per graph = ceil(0.8*512)
#define HH 128

typedef short bf16x8 __attribute__((ext_vector_type(8)));
typedef float f32x4 __attribute__((ext_vector_type(4)));

// ---------------- device scratch -------------------------------------------
__device__ unsigned short g_xb[(size_t)NT * 64];
__device__ unsigned short g_hb1[(size_t)NT * HH];
__device__ unsigned short g_hb2[(size_t)NT * HH];
__device__ unsigned short g_aggb[(size_t)NT * HH];
__device__ unsigned short g_hpb[(size_t)NT * HH];   // gated h2, old-id layout (0 for dropped)
__device__ unsigned short g_aggb64[(size_t)NT * 64];
__device__ unsigned short g_wt1[128 * 128];
__device__ unsigned short g_wtc[3 * 128 * 256];
__device__ unsigned short g_csr1u[EE];   // src id per edge, grouped by dst
__device__ unsigned short g_keptu[NT];   // 1 if node kept by SAGPool
__device__ unsigned int g_ebuck[EE];     // packed (dstLocal<<16)|src, bucketed by graph
__device__ int g_bcnt[128];
__device__ int g_bbase[129];
__device__ int g_bcur[128];
__device__ float g_gatef[NT];            // tanh(score) if kept else 0
__device__ float g_trel[NT];
__device__ float g_troot[NT];
__device__ float g_score[NT];
__device__ float g_xcat[NB * 512];
__device__ int g_rows1[NT + 1];

__device__ __forceinline__ unsigned short* ubuf(int id) {
    switch (id) {
        case 0: return g_xb;
        case 1: return g_hb1;
        case 2: return g_hb2;
        case 3: return g_aggb;
        case 4: return g_hpb;
        case 5: return g_aggb64;
        case 6: return g_wt1;
        case 7: return g_wtc;
    }
    return g_xb;
}

__device__ __forceinline__ float b2f(unsigned short u) {
    union { unsigned int i; float f; } v;
    v.i = ((unsigned int)u) << 16;
    return v.f;
}
__device__ __forceinline__ unsigned short f2b(float f) {
    unsigned int x = __float_as_uint(f);
    unsigned int r = x + 0x7fffu + ((x >> 16) & 1u);   // round-to-nearest-even
    return (unsigned short)(r >> 16);
}

// ---------------- weight prep (+ zero bucket counters) ----------------------
// tids: [0,16384) wt1 | [16384,114688) wtc | [114688,114816) bcnt=0
__global__ void k_prep_w(const float* __restrict__ W1r, const float* __restrict__ W1o,
                         const float* __restrict__ Wcr, const float* __restrict__ Wco) {
    int tid = blockIdx.x * 256 + threadIdx.x;
    if (tid < 16384) {
        int k = tid & 127, n = tid >> 7;
        float v = (k < 64) ? W1r[k * 128 + n] : W1o[(k - 64) * 128 + n];
        g_wt1[n * 128 + k] = f2b(v);
    } else if (tid < 114688) {
        int r = tid - 16384;
        int l = r >> 15;
        int k = r & 255, n = (r >> 8) & 127;
        float v = (k < 128) ? Wcr[l * 16384 + k * 128 + n]
                            : Wco[l * 16384 + (k - 128) * 128 + n];
        g_wtc[l * 32768 + n * 256 + k] = f2b(v);
    } else if (tid < 114816) {
        g_bcnt[tid - 114688] = 0;
    }
}

// ---------------- x -> bf16 -------------------------------------------------
__global__ void k_x2b(const float* __restrict__ x) {
    int tid = blockIdx.x * 256 + threadIdx.x;   // one per 4 elems
    if (tid >= NT * 64 / 4) return;
    float4 v = *(const float4*)&x[(size_t)tid * 4];
    unsigned int lo = (unsigned int)f2b(v.x) | ((unsigned int)f2b(v.y) << 16);
    unsigned int hi = (unsigned int)f2b(v.z) | ((unsigned int)f2b(v.w) << 16);
    *(uint2*)&g_xb[(size_t)tid * 4] = make_uint2(lo, hi);
}

// ---------------- CSR1 build: 2-level counting sort, no per-node global atomics
// Phase A: per-graph bucket histogram (LDS-aggregated)
__global__ __launch_bounds__(256) void k_bhist(const int* __restrict__ dst) {
    __shared__ int h[128];
    if (threadIdx.x < 128) h[threadIdx.x] = 0;
    __syncthreads();
    int e0 = (blockIdx.x * 256 + threadIdx.x) * 4;
    int4 d = *(const int4*)&dst[e0];
    atomicAdd(&h[d.x >> 9], 1);
    atomicAdd(&h[d.y >> 9], 1);
    atomicAdd(&h[d.z >> 9], 1);
    atomicAdd(&h[d.w >> 9], 1);
    __syncthreads();
    if (threadIdx.x < 128 && h[threadIdx.x]) atomicAdd(&g_bcnt[threadIdx.x], h[threadIdx.x]);
}

// Phase A2: scan 128 bucket counts -> bases + cursors
__global__ __launch_bounds__(128) void k_bscan() {
    __shared__ int s[128];
    int t = threadIdx.x;
    int v = g_bcnt[t];
    s[t] = v;
    __syncthreads();
    for (int off = 1; off < 128; off <<= 1) {
        int u = (t >= off) ? s[t - off] : 0;
        __syncthreads();
        s[t] += u;
        __syncthreads();
    }
    g_bbase[t] = s[t] - v;
    g_bcur[t] = s[t] - v;
    if (t == 127) g_bbase[128] = s[127];
}

// Phase B: scatter packed edges into bucket regions (block-level reservation)
__global__ __launch_bounds__(256) void k_bscatter(const int* __restrict__ src,
                                                  const int* __restrict__ dst) {
    __shared__ int h[128];
    __shared__ int base[128];
    if (threadIdx.x < 128) h[threadIdx.x] = 0;
    __syncthreads();
    int e0 = (blockIdx.x * 256 + threadIdx.x) * 4;
    int4 s = *(const int4*)&src[e0];
    int4 d = *(const int4*)&dst[e0];
    int b0 = d.x >> 9, b1 = d.y >> 9, b2 = d.z >> 9, b3 = d.w >> 9;
    atomicAdd(&h[b0], 1);
    atomicAdd(&h[b1], 1);
    atomicAdd(&h[b2], 1);
    atomicAdd(&h[b3], 1);
    __syncthreads();
    if (threadIdx.x < 128) {
        int c = h[threadIdx.x];
        base[threadIdx.x] = c ? atomicAdd(&g_bcur[threadIdx.x], c) : 0;
        h[threadIdx.x] = 0;
    }
    __syncthreads();
    int r0 = atomicAdd(&h[b0], 1);
    g_ebuck[base[b0] + r0] = ((unsigned int)(d.x & 511) << 16) | (unsigned int)s.x;
    int r1 = atomicAdd(&h[b1], 1);
    g_ebuck[base[b1] + r1] = ((unsigned int)(d.y & 511) << 16) | (unsigned int)s.y;
    int r2 = atomicAdd(&h[b2], 1);
    g_ebuck[base[b2] + r2] = ((unsigned int)(d.z & 511) << 16) | (unsigned int)s.z;
    int r3 = atomicAdd(&h[b3], 1);
    g_ebuck[base[b3] + r3] = ((unsigned int)(d.w & 511) << 16) | (unsigned int)s.w;
}

// Phase C: per-graph local CSR build in LDS
__global__ __launch_bounds__(512) void k_bcsr() {
    __shared__ int hist[512];
    __shared__ int offs[512];
    __shared__ int cur[512];
    int g = blockIdx.x, t = threadIdx.x;
    hist[t] = 0;
    cur[t] = 0;
    __syncthreads();
    int b0 = g_bbase[g], b1 = g_bbase[g + 1];
    for (int e = b0 + t; e < b1; e += 512) {
        unsigned int p = g_ebuck[e];
        atomicAdd(&hist[p >> 16], 1);
    }
    __syncthreads();
    int v = hist[t];
    offs[t] = v;
    __syncthreads();
    for (int off = 1; off < 512; off <<= 1) {
        int u = (t >= off) ? offs[t - off] : 0;
        __syncthreads();
        offs[t] += u;
        __syncthreads();
    }
    int excl = offs[t] - v;
    g_rows1[g * 512 + t] = b0 + excl;
    if (t == 511) g_rows1[g * 512 + 512] = b0 + excl + v;
    __syncthreads();
    offs[t] = excl;
    __syncthreads();
    for (int e = b0 + t; e < b1; e += 512) {
        unsigned int p = g_ebuck[e];
        int dl = p >> 16;
        int r = atomicAdd(&cur[dl], 1);
        g_csr1u[b0 + offs[dl] + r] = (unsigned short)(p & 0xFFFFu);
    }
}

// ---------------- mean aggregation (bf16 gather, unroll-4) ------------------
// UK=1: denominator = # kept neighbors (broadcast ushort gather), numerator
// relies on zero rows for dropped nodes.
template <int D, int UK>
__global__ __launch_bounds__(256) void k_agg_mean(int hId, int outId, int n) {
    const unsigned short* h = ubuf(hId);
    unsigned short* out = ubuf(outId);
    const int TPN = D / 8;          // 8 bf16 = 16B per thread
    const int npb = 256 / TPN;
    int local = threadIdx.x / TPN;
    int t = threadIdx.x % TPN;
    int node = blockIdx.x * npb + local;
    if (node >= n) return;
    int r0 = g_rows1[node], r1 = g_rows1[node + 1];
    float acc[8];
#pragma unroll
    for (int i = 0; i < 8; i++) acc[i] = 0.f;
    int kc = 0;
    const unsigned short* ht = h + t * 8;
#define ACCV(v)                                                  \
    acc[0] += b2f((unsigned short)(v.x & 0xffff));               \
    acc[1] += b2f((unsigned short)(v.x >> 16));                  \
    acc[2] += b2f((unsigned short)(v.y & 0xffff));               \
    acc[3] += b2f((unsigned short)(v.y >> 16));                  \
    acc[4] += b2f((unsigned short)(v.z & 0xffff));               \
    acc[5] += b2f((unsigned short)(v.z >> 16));                  \
    acc[6] += b2f((unsigned short)(v.w & 0xffff));               \
    acc[7] += b2f((unsigned short)(v.w >> 16));
    int e = r0;
    for (; e + 4 <= r1; e += 4) {
        int i0 = g_csr1u[e], i1 = g_csr1u[e + 1], i2 = g_csr1u[e + 2], i3 = g_csr1u[e + 3];
        uint4 v0 = *(const uint4*)&ht[(size_t)i0 * D];
        uint4 v1 = *(const uint4*)&ht[(size_t)i1 * D];
        uint4 v2 = *(const uint4*)&ht[(size_t)i2 * D];
        uint4 v3 = *(const uint4*)&ht[(size_t)i3 * D];
        if (UK) kc += (int)g_keptu[i0] + (int)g_keptu[i1] + (int)g_keptu[i2] + (int)g_keptu[i3];
        ACCV(v0) ACCV(v1) ACCV(v2) ACCV(v3)
    }
    for (; e < r1; e++) {
        int i0 = g_csr1u[e];
        uint4 v0 = *(const uint4*)&ht[(size_t)i0 * D];
        if (UK) kc += (int)g_keptu[i0];
        ACCV(v0)
    }
#undef ACCV
    int c = UK ? kc : (r1 - r0);
    float inv = 1.0f / (float)(c > 0 ? c : 1);
    uint4 o;
    o.x = (unsigned int)f2b(acc[0] * inv) | ((unsigned int)f2b(acc[1] * inv) << 16);
    o.y = (unsigned int)f2b(acc[2] * inv) | ((unsigned int)f2b(acc[3] * inv) << 16);
    o.z = (unsigned int)f2b(acc[4] * inv) | ((unsigned int)f2b(acc[5] * inv) << 16);
    o.w = (unsigned int)f2b(acc[6] * inv) | ((unsigned int)f2b(acc[7] * inv) << 16);
    *(uint4*)&out[(size_t)node * D + t * 8] = o;
}

// ---------------- MFMA GEMM: out = relu([A|B] @ W + bias), N=128 ------------
// MASKED=1: rows with g_keptu[r]==0 are forced to zero.
template <int KA, int KB, int MASKED>
__global__ __launch_bounds__(256) void k_mm(int aId, int bId, int wId, int wOfs,
                                            const float* __restrict__ bias, int outId) {
    const unsigned short* Ap = ubuf(aId);
    const unsigned short* Bp = ubuf(bId);
    const unsigned short* Wt = ubuf(wId) + wOfs;
    unsigned short* out = ubuf(outId);
    const int K = KA + KB;
    int lane = threadIdx.x & 63;
    int w = threadIdx.x >> 6;
    int n16 = lane & 15, quad = lane >> 4;
    int rowbase = blockIdx.x * 128 + w * 32;
    f32x4 acc[2][8];
#pragma unroll
    for (int rt = 0; rt < 2; rt++)
#pragma unroll
        for (int ct = 0; ct < 8; ct++)
#pragma unroll
            for (int i = 0; i < 4; i++) acc[rt][ct][i] = 0.f;

#pragma unroll
    for (int ks = 0; ks < K / 32; ks++) {
        int k0 = ks * 32;
        const unsigned short* S;
        int kk, str;
        if (k0 < KA) { S = Ap; kk = k0; str = KA; }
        else         { S = Bp; kk = k0 - KA; str = KB; }
        bf16x8 a0 = *(const bf16x8*)&S[(size_t)(rowbase + n16) * str + kk + quad * 8];
        bf16x8 a1 = *(const bf16x8*)&S[(size_t)(rowbase + 16 + n16) * str + kk + quad * 8];
#pragma unroll
        for (int ct = 0; ct < 8; ct++) {
            bf16x8 b = *(const bf16x8*)&Wt[(size_t)(ct * 16 + n16) * K + k0 + quad * 8];
            acc[0][ct] = __builtin_amdgcn_mfma_f32_16x16x32_bf16(a0, b, acc[0][ct], 0, 0, 0);
            acc[1][ct] = __builtin_amdgcn_mfma_f32_16x16x32_bf16(a1, b, acc[1][ct], 0, 0, 0);
        }
    }
#pragma unroll
    for (int rt = 0; rt < 2; rt++) {
        float m[4];
#pragma unroll
        for (int i = 0; i < 4; i++) {
            int r = rowbase + rt * 16 + quad * 4 + i;
            m[i] = (!MASKED || g_keptu[r]) ? 1.0f : 0.0f;
        }
#pragma unroll
        for (int ct = 0; ct < 8; ct++) {
            int c = ct * 16 + n16;
            float bv = bias[c];
#pragma unroll
            for (int i = 0; i < 4; i++) {
                int r = rowbase + rt * 16 + quad * 4 + i;
                out[(size_t)r * 128 + c] = f2b(fmaxf(acc[rt][ct][i] + bv, 0.f) * m[i]);
            }
        }
    }
}

// ---------------- per-graph mean pool into xcat column block ----------------
// sums `rows` rows per graph, multiplies by `inv` (dropped rows are zero)
__global__ __launch_bounds__(512) void k_pool(int hId, float inv, int col0) {
    const unsigned short* h = ubuf(hId);
    __shared__ float acc[4][128];
    int g = blockIdx.x, t = threadIdx.x;
    int sub = t >> 7, d = t & 127;
    float s = 0.f;
    for (int i = sub; i < 512; i += 4) s += b2f(h[(size_t)(g * 512 + i) * 128 + d]);
    acc[sub][d] = s;
    __syncthreads();
    if (t < 128) {
        float v = acc[0][t] + acc[1][t] + acc[2][t] + acc[3][t];
        g_xcat[g * 512 + col0 + t] = v * inv;
    }
}

// ---------------- SAGPool scoring -------------------------------------------
__global__ __launch_bounds__(256) void k_score_dots(const float* __restrict__ pwr,
                                                    const float* __restrict__ pwt) {
    int wid = (blockIdx.x * 256 + threadIdx.x) >> 6;
    int lane = threadIdx.x & 63;
    if (wid >= NT) return;
    const unsigned short* row = g_hb2 + (size_t)wid * 128;
    float h0 = b2f(row[lane]), h1 = b2f(row[lane + 64]);
    float a = h0 * pwr[lane] + h1 * pwr[lane + 64];
    float b = h0 * pwt[lane] + h1 * pwt[lane + 64];
    for (int off = 32; off > 0; off >>= 1) {
        a += __shfl_down(a, off);
        b += __shfl_down(b, off);
    }
    if (lane == 0) { g_trel[wid] = a; g_troot[wid] = b; }
}

__global__ void k_score_agg(const float* __restrict__ pb) {
    int i = blockIdx.x * blockDim.x + threadIdx.x;
    if (i >= NT) return;
    int r0 = g_rows1[i], r1 = g_rows1[i + 1];
    float s = 0.f;
    int e = r0;
    for (; e + 4 <= r1; e += 4) {
        float s0 = g_trel[g_csr1u[e]];
        float s1 = g_trel[g_csr1u[e + 1]];
        float s2 = g_trel[g_csr1u[e + 2]];
        float s3 = g_trel[g_csr1u[e + 3]];
        s += (s0 + s1) + (s2 + s3);
    }
    for (; e < r1; e++) s += g_trel[g_csr1u[e]];
    g_score[i] = s + g_troot[i] + pb[0];
}

// per-graph bitonic sort of 512 scores (desc value, asc index — matches lax.top_k)
// writes kept flag + gate on OLD node ids
__global__ __launch_bounds__(256) void k_topk() {
    __shared__ float sv[512];
    __shared__ int si[512];
    int g = blockIdx.x, t = threadIdx.x;
    for (int i = t; i < 512; i += 256) { sv[i] = g_score[g * 512 + i]; si[i] = i; }
    __syncthreads();
    for (int k = 2; k <= 512; k <<= 1) {
        for (int j = k >> 1; j > 0; j >>= 1) {
            for (int i = t; i < 512; i += 256) {
                int p = i ^ j;
                if (p > i) {
                    float va = sv[i], vb = sv[p];
                    int ia = si[i], ib = si[p];
                    bool aFirst = (va > vb) || (va == vb && ia < ib);
                    bool up = ((i & k) == 0);
                    if (up != aFirst) { sv[i] = vb; sv[p] = va; si[i] = ib; si[p] = ia; }
                }
            }
            __syncthreads();
        }
    }
    for (int r = t; r < 512; r += 256) {
        int old = g * 512 + si[r];
        if (r < KK) {
            g_gatef[old] = tanhf(sv[r]);
            g_keptu[old] = 1;
        } else {
            g_gatef[old] = 0.f;
            g_keptu[old] = 0;
        }
    }
}

// dense gate in old-id layout: hp[o] = h2[o] * gate[o]  (0 for dropped)
__global__ void k_gate() {
    int tid = blockIdx.x * blockDim.x + threadIdx.x;
    if (tid >= NT * 16) return;          // 8 bf16 per thread
    int nn = tid >> 4, c = tid & 15;
    float gt = g_gatef[nn];
    uint4 v = *(const uint4*)&g_hb2[(size_t)nn * 128 + c * 8];
    uint4 o;
    o.x = (unsigned int)f2b(b2f((unsigned short)(v.x & 0xffff)) * gt) |
          ((unsigned int)f2b(b2f((unsigned short)(v.x >> 16)) * gt) << 16);
    o.y = (unsigned int)f2b(b2f((unsigned short)(v.y & 0xffff)) * gt) |
          ((unsigned int)f2b(b2f((unsigned short)(v.y >> 16)) * gt) << 16);
    o.z = (unsigned int)f2b(b2f((unsigned short)(v.z & 0xffff)) * gt) |
          ((unsigned int)f2b(b2f((unsigned short)(v.z >> 16)) * gt) << 16);
    o.w = (unsigned int)f2b(b2f((unsigned short)(v.w & 0xffff)) * gt) |
          ((unsigned int)f2b(b2f((unsigned short)(v.w >> 16)) * gt) << 16);
    *(uint4*)&g_hpb[(size_t)nn * 128 + c * 8] = o;
}

// ---------------- MLP head + log_softmax ------------------------------------
__global__ __launch_bounds__(128) void k_head(const float* __restrict__ W1, const float* __restrict__ b1,
                                              const float* __restrict__ W2, const float* __restrict__ b2,
                                              float* __restrict__ out) {
    __shared__ float xr[512];
    __shared__ float r0[128], r1[128];
    int g = blockIdx.x, t = threadIdx.x;
    for (int i = t; i < 512; i += 128) xr[i] = g_xcat[g * 512 + i];
    __syncthreads();
    float acc = b1[t];
    for (int k = 0; k < 512; k++) acc += xr[k] * W1[k * 128 + t];
    acc = fmaxf(acc, 0.f);
    r0[t] = acc * W2[t * 2 + 0];
    r1[t] = acc * W2[t * 2 + 1];
    __syncthreads();
    for (int off = 64; off > 0; off >>= 1) {
        if (t < off) { r0[t] += r0[t + off]; r1[t] += r1[t + off]; }
        __syncthreads();
    }
    if (t == 0) {
        float z0 = r0[0] + b2[0], z1 = r1[0] + b2[1];
        float m = fmaxf(z0, z1);
        float l = m + logf(expf(z0 - m) + expf(z1 - m));
        out[g * 2 + 0] = z0 - l;
        out[g * 2 + 1] = z1 - l;
    }
}

// ---------------- launch -----------------------------------------------------
extern "C" void kernel_launch(void* const* d_in, const int* in_sizes, int n_in,
                              void* d_out, int out_size, void* d_ws, size_t ws_size,
                              hipStream_t stream) {
    const float* x = (const float*)d_in[0];
    const int* ei = (const int*)d_in[1];
    const int* src = ei;
    const int* dst = ei + EE;
    const float* W1r = (const float*)d_in[3];
    const float* W1o = (const float*)d_in[4];
    const float* b1 = (const float*)d_in[5];
    const float* Wcr = (const float*)d_in[6];
    const float* Wco = (const float*)d_in[7];
    const float* bc = (const float*)d_in[8];
    const float* pwr = (const float*)d_in[9];
    const float* pwt = (const float*)d_in[10];
    const float* pb = (const float*)d_in[11];
    const float* l1W = (const float*)d_in[12];
    const float* l1b = (const float*)d_in[13];
    const float* l2W = (const float*)d_in[14];
    const float* l2b = (const float*)d_in[15];
    float* out = (float*)d_out;

    // ---- prep: weights -> bf16 [n][K], x -> bf16 ----
    k_prep_w<<<449, 256, 0, stream>>>(W1r, W1o, Wcr, Wco);
    k_x2b<<<4096, 256, 0, stream>>>(x);

    // ---- CSR1 via counting sort (no per-node global atomics) ----
    k_bhist<<<1024, 256, 0, stream>>>(dst);
    k_bscan<<<1, 128, 0, stream>>>();
    k_bscatter<<<1024, 256, 0, stream>>>(src, dst);
    k_bcsr<<<128, 512, 0, stream>>>();

    // ---- conv1: agg64(xb) ; hb1 = relu([agg|xb] @ wt1 + b1) ----
    k_agg_mean<64, 0><<<NT / 32, 256, 0, stream>>>(0, 5, NT);
    k_mm<64, 64, 0><<<NT / 128, 256, 0, stream>>>(5, 0, 6, 0, b1, 1);
    k_pool<<<NB, 512, 0, stream>>>(1, 1.0f / 512.0f, 0);

    // ---- conv2 -> hb2 ----
    k_agg_mean<128, 0><<<NT / 16, 256, 0, stream>>>(1, 3, NT);
    k_mm<128, 128, 0><<<NT / 128, 256, 0, stream>>>(3, 1, 7, 0, bc, 2);
    k_pool<<<NB, 512, 0, stream>>>(2, 1.0f / 512.0f, 128);

    // ---- SAGPool: score (add-aggr), per-graph top-410, dense gate ----
    k_score_dots<<<NT * 64 / 256, 256, 0, stream>>>(pwr, pwt);
    k_score_agg<<<NT / 256, 256, 0, stream>>>(pb);
    k_topk<<<NB, 256, 0, stream>>>();
    k_gate<<<NT * 16 / 256, 256, 0, stream>>>();

    // ---- conv3 in old-id space (masked) -> hb1 ----
    k_agg_mean<128, 1><<<NT / 16, 256, 0, stream>>>(4, 3, NT);
    k_mm<128, 128, 1><<<NT / 128, 256, 0, stream>>>(3, 4, 7, 32768, bc + 128, 1);
    k_pool<<<NB, 512, 0, stream>>>(1, 1.0f / 410.0f, 256);

    // ---- conv4 -> hb2 ----
    k_agg_mean<128, 1><<<NT / 16, 256, 0, stream>>>(1, 3, NT);
    k_mm<128, 128, 1><<<NT / 128, 256, 0, stream>>>(3, 1, 7, 65536, bc + 256, 2);
    k_pool<<<NB, 512, 0, stream>>>(2, 1.0f / 410.0f, 384);

    // ---- head ----
    k_head<<<NB, 128, 0, stream>>>(l1W, l1b, l2W, l2b, out);
}

// Round 5
// 500.957 us; speedup vs baseline: 1.8037x; 1.2842x over previous
//
#include <hip/hip_runtime.h>
#include <math.h>

#define NT 65536
#define EE 1048576
#define NB 128
#define KK 410          // kept nodes per graph = ceil(0.8*512)
#define HH 128

typedef short bf16x8 __attribute__((ext_vector_type(8)));
typedef float f32x4 __attribute__((ext_vector_type(4)));

// ---------------- device scratch -------------------------------------------
__device__ unsigned short g_xb[(size_t)NT * 64];
__device__ unsigned short g_hb1[(size_t)NT * HH];
__device__ unsigned short g_hb2[(size_t)NT * HH];
__device__ unsigned short g_aggb[(size_t)NT * HH];
__device__ unsigned short g_hpb[(size_t)NT * HH];   // gated h2, old-id layout (0 for dropped)
__device__ unsigned short g_aggb64[(size_t)NT * 64];
__device__ unsigned short g_wt1[128 * 128];
__device__ unsigned short g_wtc[3 * 128 * 256];
__device__ unsigned short g_csr1u[EE];   // src id per edge, grouped by dst
__device__ unsigned short g_keptu[NT];   // 1 if node kept by SAGPool
__device__ unsigned int g_ebuck[EE];     // packed (dstLocal<<16)|src, bucketed by graph
__device__ int g_bcnt[128];
__device__ int g_bbase[129];
__device__ int g_bcur[128];
__device__ float g_trel[NT];
__device__ float g_troot[NT];
__device__ float g_score[NT];
__device__ float g_kinv[NT];             // 1/max(kept-neighbor count,1)
__device__ float g_xc4[4 * NB * 4 * 128]; // pooled partials [sec][graph][quarter][128]
__device__ int g_rows1[NT + 1];

__device__ __forceinline__ unsigned short* ubuf(int id) {
    switch (id) {
        case 0: return g_xb;
        case 1: return g_hb1;
        case 2: return g_hb2;
        case 3: return g_aggb;
        case 4: return g_hpb;
        case 5: return g_aggb64;
        case 6: return g_wt1;
        case 7: return g_wtc;
    }
    return g_xb;
}

__device__ __forceinline__ float b2f(unsigned short u) {
    union { unsigned int i; float f; } v;
    v.i = ((unsigned int)u) << 16;
    return v.f;
}
__device__ __forceinline__ unsigned short f2b(float f) {
    unsigned int x = __float_as_uint(f);
    unsigned int r = x + 0x7fffu + ((x >> 16) & 1u);   // round-to-nearest-even
    return (unsigned short)(r >> 16);
}

// ---------------- prep: x->bf16, weights->bf16 [n][K], zero bcnt ------------
// tid ranges: [0,1048576) x quads | +16384 wt1 | +98304 wtc | +128 bcnt
__global__ void k_prep(const float* __restrict__ x,
                       const float* __restrict__ W1r, const float* __restrict__ W1o,
                       const float* __restrict__ Wcr, const float* __restrict__ Wco) {
    int tid = blockIdx.x * 256 + threadIdx.x;
    if (tid < 1048576) {
        float4 v = *(const float4*)&x[(size_t)tid * 4];
        unsigned int lo = (unsigned int)f2b(v.x) | ((unsigned int)f2b(v.y) << 16);
        unsigned int hi = (unsigned int)f2b(v.z) | ((unsigned int)f2b(v.w) << 16);
        *(uint2*)&g_xb[(size_t)tid * 4] = make_uint2(lo, hi);
    } else if (tid < 1048576 + 16384) {
        int r = tid - 1048576;
        int k = r & 127, n = r >> 7;
        float v = (k < 64) ? W1r[k * 128 + n] : W1o[(k - 64) * 128 + n];
        g_wt1[n * 128 + k] = f2b(v);
    } else if (tid < 1048576 + 16384 + 98304) {
        int r = tid - (1048576 + 16384);
        int l = r >> 15;
        int k = r & 255, n = (r >> 8) & 127;
        float v = (k < 128) ? Wcr[l * 16384 + k * 128 + n]
                            : Wco[l * 16384 + (k - 128) * 128 + n];
        g_wtc[l * 32768 + n * 256 + k] = f2b(v);
    } else if (tid < 1048576 + 16384 + 98304 + 128) {
        g_bcnt[tid - (1048576 + 16384 + 98304)] = 0;
    }
}

// ---------------- CSR1 build: 2-level counting sort -------------------------
__global__ __launch_bounds__(256) void k_bhist(const int* __restrict__ dst) {
    __shared__ int h[128];
    if (threadIdx.x < 128) h[threadIdx.x] = 0;
    __syncthreads();
    int e0 = (blockIdx.x * 256 + threadIdx.x) * 4;
    int4 d = *(const int4*)&dst[e0];
    atomicAdd(&h[d.x >> 9], 1);
    atomicAdd(&h[d.y >> 9], 1);
    atomicAdd(&h[d.z >> 9], 1);
    atomicAdd(&h[d.w >> 9], 1);
    __syncthreads();
    if (threadIdx.x < 128 && h[threadIdx.x]) atomicAdd(&g_bcnt[threadIdx.x], h[threadIdx.x]);
}

__global__ __launch_bounds__(128) void k_bscan() {
    __shared__ int s[128];
    int t = threadIdx.x;
    int v = g_bcnt[t];
    s[t] = v;
    __syncthreads();
    for (int off = 1; off < 128; off <<= 1) {
        int u = (t >= off) ? s[t - off] : 0;
        __syncthreads();
        s[t] += u;
        __syncthreads();
    }
    g_bbase[t] = s[t] - v;
    g_bcur[t] = s[t] - v;
    if (t == 127) g_bbase[128] = s[127];
}

__global__ __launch_bounds__(256) void k_bscatter(const int* __restrict__ src,
                                                  const int* __restrict__ dst) {
    __shared__ int h[128];
    __shared__ int base[128];
    if (threadIdx.x < 128) h[threadIdx.x] = 0;
    __syncthreads();
    int e0 = (blockIdx.x * 256 + threadIdx.x) * 4;
    int4 s = *(const int4*)&src[e0];
    int4 d = *(const int4*)&dst[e0];
    int b0 = d.x >> 9, b1 = d.y >> 9, b2 = d.z >> 9, b3 = d.w >> 9;
    atomicAdd(&h[b0], 1);
    atomicAdd(&h[b1], 1);
    atomicAdd(&h[b2], 1);
    atomicAdd(&h[b3], 1);
    __syncthreads();
    if (threadIdx.x < 128) {
        int c = h[threadIdx.x];
        base[threadIdx.x] = c ? atomicAdd(&g_bcur[threadIdx.x], c) : 0;
        h[threadIdx.x] = 0;
    }
    __syncthreads();
    int r0 = atomicAdd(&h[b0], 1);
    g_ebuck[base[b0] + r0] = ((unsigned int)(d.x & 511) << 16) | (unsigned int)s.x;
    int r1 = atomicAdd(&h[b1], 1);
    g_ebuck[base[b1] + r1] = ((unsigned int)(d.y & 511) << 16) | (unsigned int)s.y;
    int r2 = atomicAdd(&h[b2], 1);
    g_ebuck[base[b2] + r2] = ((unsigned int)(d.z & 511) << 16) | (unsigned int)s.z;
    int r3 = atomicAdd(&h[b3], 1);
    g_ebuck[base[b3] + r3] = ((unsigned int)(d.w & 511) << 16) | (unsigned int)s.w;
}

__global__ __launch_bounds__(512) void k_bcsr() {
    __shared__ int hist[512];
    __shared__ int offs[512];
    __shared__ int cur[512];
    int g = blockIdx.x, t = threadIdx.x;
    hist[t] = 0;
    cur[t] = 0;
    __syncthreads();
    int b0 = g_bbase[g], b1 = g_bbase[g + 1];
    for (int e = b0 + t; e < b1; e += 512) {
        unsigned int p = g_ebuck[e];
        atomicAdd(&hist[p >> 16], 1);
    }
    __syncthreads();
    int v = hist[t];
    offs[t] = v;
    __syncthreads();
    for (int off = 1; off < 512; off <<= 1) {
        int u = (t >= off) ? offs[t - off] : 0;
        __syncthreads();
        offs[t] += u;
        __syncthreads();
    }
    int excl = offs[t] - v;
    g_rows1[g * 512 + t] = b0 + excl;
    if (t == 511) g_rows1[g * 512 + 512] = b0 + excl + v;
    __syncthreads();
    offs[t] = excl;
    __syncthreads();
    for (int e = b0 + t; e < b1; e += 512) {
        unsigned int p = g_ebuck[e];
        int dl = p >> 16;
        int r = atomicAdd(&cur[dl], 1);
        g_csr1u[b0 + offs[dl] + r] = (unsigned short)(p & 0xFFFFu);
    }
}

// ---------------- mean aggregation (bf16 gather, unroll-8) ------------------
// KC: 0 = denom deg; 1 = denom kept-count (gather keptu), store g_kinv;
//     2 = read g_kinv
template <int D, int KC>
__global__ __launch_bounds__(256) void k_agg(int hId, int outId) {
    const unsigned short* h = ubuf(hId);
    unsigned short* out = ubuf(outId);
    const int TPN = D / 8;          // 8 bf16 = 16B per thread
    const int npb = 256 / TPN;
    int local = threadIdx.x / TPN;
    int t = threadIdx.x % TPN;
    int node = blockIdx.x * npb + local;
    int r0 = g_rows1[node], r1 = g_rows1[node + 1];
    float kinv_pre = (KC == 2) ? g_kinv[node] : 0.f;
    float acc[8];
#pragma unroll
    for (int i = 0; i < 8; i++) acc[i] = 0.f;
    int kc = 0;
    const unsigned short* ht = h + t * 8;
#define ACCV(v)                                                  \
    acc[0] += b2f((unsigned short)(v.x & 0xffff));               \
    acc[1] += b2f((unsigned short)(v.x >> 16));                  \
    acc[2] += b2f((unsigned short)(v.y & 0xffff));               \
    acc[3] += b2f((unsigned short)(v.y >> 16));                  \
    acc[4] += b2f((unsigned short)(v.z & 0xffff));               \
    acc[5] += b2f((unsigned short)(v.z >> 16));                  \
    acc[6] += b2f((unsigned short)(v.w & 0xffff));               \
    acc[7] += b2f((unsigned short)(v.w >> 16));
    int e = r0;
    for (; e + 8 <= r1; e += 8) {
        int i0 = g_csr1u[e], i1 = g_csr1u[e + 1], i2 = g_csr1u[e + 2], i3 = g_csr1u[e + 3];
        int i4 = g_csr1u[e + 4], i5 = g_csr1u[e + 5], i6 = g_csr1u[e + 6], i7 = g_csr1u[e + 7];
        uint4 v0 = *(const uint4*)&ht[(size_t)i0 * D];
        uint4 v1 = *(const uint4*)&ht[(size_t)i1 * D];
        uint4 v2 = *(const uint4*)&ht[(size_t)i2 * D];
        uint4 v3 = *(const uint4*)&ht[(size_t)i3 * D];
        uint4 v4 = *(const uint4*)&ht[(size_t)i4 * D];
        uint4 v5 = *(const uint4*)&ht[(size_t)i5 * D];
        uint4 v6 = *(const uint4*)&ht[(size_t)i6 * D];
        uint4 v7 = *(const uint4*)&ht[(size_t)i7 * D];
        if (KC == 1)
            kc += (int)g_keptu[i0] + (int)g_keptu[i1] + (int)g_keptu[i2] + (int)g_keptu[i3]
                + (int)g_keptu[i4] + (int)g_keptu[i5] + (int)g_keptu[i6] + (int)g_keptu[i7];
        ACCV(v0) ACCV(v1) ACCV(v2) ACCV(v3) ACCV(v4) ACCV(v5) ACCV(v6) ACCV(v7)
    }
    for (; e + 4 <= r1; e += 4) {
        int i0 = g_csr1u[e], i1 = g_csr1u[e + 1], i2 = g_csr1u[e + 2], i3 = g_csr1u[e + 3];
        uint4 v0 = *(const uint4*)&ht[(size_t)i0 * D];
        uint4 v1 = *(const uint4*)&ht[(size_t)i1 * D];
        uint4 v2 = *(const uint4*)&ht[(size_t)i2 * D];
        uint4 v3 = *(const uint4*)&ht[(size_t)i3 * D];
        if (KC == 1)
            kc += (int)g_keptu[i0] + (int)g_keptu[i1] + (int)g_keptu[i2] + (int)g_keptu[i3];
        ACCV(v0) ACCV(v1) ACCV(v2) ACCV(v3)
    }
    for (; e < r1; e++) {
        int i0 = g_csr1u[e];
        uint4 v0 = *(const uint4*)&ht[(size_t)i0 * D];
        if (KC == 1) kc += (int)g_keptu[i0];
        ACCV(v0)
    }
#undef ACCV
    float inv;
    if (KC == 0) {
        int c = r1 - r0;
        inv = 1.0f / (float)(c > 0 ? c : 1);
    } else if (KC == 1) {
        inv = 1.0f / (float)(kc > 0 ? kc : 1);
        if (t == 0) g_kinv[node] = inv;
    } else {
        inv = kinv_pre;
    }
    uint4 o;
    o.x = (unsigned int)f2b(acc[0] * inv) | ((unsigned int)f2b(acc[1] * inv) << 16);
    o.y = (unsigned int)f2b(acc[2] * inv) | ((unsigned int)f2b(acc[3] * inv) << 16);
    o.z = (unsigned int)f2b(acc[4] * inv) | ((unsigned int)f2b(acc[5] * inv) << 16);
    o.w = (unsigned int)f2b(acc[6] * inv) | ((unsigned int)f2b(acc[7] * inv) << 16);
    *(uint4*)&out[(size_t)node * D + t * 8] = o;
}

// ---------------- MFMA GEMM + fused epilogues --------------------------------
// out = relu([A|B] @ W + bias) (row-masked if MASKED); epilogues:
//  - pool partials: per-block column sums -> g_xc4[sec][g][quarter][128]
//  - DOTS (conv2): g_trel/g_troot row dots with pwr/pwt
template <int KA, int KB, int MASKED, int DOTS>
__global__ __launch_bounds__(256) void k_mm(int aId, int bId, int wId, int wOfs,
                                            const float* __restrict__ bias, int outId,
                                            int sec,
                                            const float* __restrict__ pwr,
                                            const float* __restrict__ pwt) {
    const unsigned short* Ap = ubuf(aId);
    const unsigned short* Bp = ubuf(bId);
    const unsigned short* Wt = ubuf(wId) + wOfs;
    unsigned short* out = ubuf(outId);
    __shared__ float s[128];
    const int K = KA + KB;
    int lane = threadIdx.x & 63;
    int w = threadIdx.x >> 6;
    int n16 = lane & 15, quad = lane >> 4;
    int rowbase = blockIdx.x * 128 + w * 32;
    int g = blockIdx.x >> 2, qb = blockIdx.x & 3;
    f32x4 acc[2][8];
#pragma unroll
    for (int rt = 0; rt < 2; rt++)
#pragma unroll
        for (int ct = 0; ct < 8; ct++)
#pragma unroll
            for (int i = 0; i < 4; i++) acc[rt][ct][i] = 0.f;

#pragma unroll
    for (int ks = 0; ks < K / 32; ks++) {
        int k0 = ks * 32;
        const unsigned short* S;
        int kk, str;
        if (k0 < KA) { S = Ap; kk = k0; str = KA; }
        else         { S = Bp; kk = k0 - KA; str = KB; }
        bf16x8 a0 = *(const bf16x8*)&S[(size_t)(rowbase + n16) * str + kk + quad * 8];
        bf16x8 a1 = *(const bf16x8*)&S[(size_t)(rowbase + 16 + n16) * str + kk + quad * 8];
#pragma unroll
        for (int ct = 0; ct < 8; ct++) {
            bf16x8 b = *(const bf16x8*)&Wt[(size_t)(ct * 16 + n16) * K + k0 + quad * 8];
            acc[0][ct] = __builtin_amdgcn_mfma_f32_16x16x32_bf16(a0, b, acc[0][ct], 0, 0, 0);
            acc[1][ct] = __builtin_amdgcn_mfma_f32_16x16x32_bf16(a1, b, acc[1][ct], 0, 0, 0);
        }
    }

    // bias + relu + mask, store, keep values in acc
    if (threadIdx.x < 128) s[threadIdx.x] = 0.f;
#pragma unroll
    for (int rt = 0; rt < 2; rt++) {
        float m[4];
#pragma unroll
        for (int i = 0; i < 4; i++) {
            int r = rowbase + rt * 16 + quad * 4 + i;
            m[i] = (!MASKED || g_keptu[r]) ? 1.0f : 0.0f;
        }
#pragma unroll
        for (int ct = 0; ct < 8; ct++) {
            int c = ct * 16 + n16;
            float bv = bias[c];
#pragma unroll
            for (int i = 0; i < 4; i++) {
                int r = rowbase + rt * 16 + quad * 4 + i;
                float v = fmaxf(acc[rt][ct][i] + bv, 0.f) * m[i];
                acc[rt][ct][i] = v;
                out[(size_t)r * 128 + c] = f2b(v);
            }
        }
    }
    __syncthreads();

    // pool epilogue: column sums over this block's 128 rows
#pragma unroll
    for (int ct = 0; ct < 8; ct++) {
        float p = 0.f;
#pragma unroll
        for (int rt = 0; rt < 2; rt++)
#pragma unroll
            for (int i = 0; i < 4; i++) p += acc[rt][ct][i];
        p += __shfl_xor(p, 16);
        p += __shfl_xor(p, 32);
        if (quad == 0) atomicAdd(&s[ct * 16 + n16], p);
    }

    // DOTS epilogue (conv2): row dots with pwr/pwt
    if (DOTS) {
        float pr[8], pt[8];
#pragma unroll
        for (int ct = 0; ct < 8; ct++) {
            pr[ct] = pwr[ct * 16 + n16];
            pt[ct] = pwt[ct * 16 + n16];
        }
#pragma unroll
        for (int rt = 0; rt < 2; rt++)
#pragma unroll
            for (int i = 0; i < 4; i++) {
                float dr = 0.f, dt = 0.f;
#pragma unroll
                for (int ct = 0; ct < 8; ct++) {
                    dr += acc[rt][ct][i] * pr[ct];
                    dt += acc[rt][ct][i] * pt[ct];
                }
                dr += __shfl_xor(dr, 1); dt += __shfl_xor(dt, 1);
                dr += __shfl_xor(dr, 2); dt += __shfl_xor(dt, 2);
                dr += __shfl_xor(dr, 4); dt += __shfl_xor(dt, 4);
                dr += __shfl_xor(dr, 8); dt += __shfl_xor(dt, 8);
                if (n16 == 0) {
                    int r = rowbase + rt * 16 + quad * 4 + i;
                    g_trel[r] = dr;
                    g_troot[r] = dt;
                }
            }
    }
    __syncthreads();
    if (threadIdx.x < 128)
        g_xc4[((sec * NB + g) * 4 + qb) * 128 + threadIdx.x] = s[threadIdx.x];
}

// ---------------- SAGPool scoring -------------------------------------------
__global__ void k_score_agg(const float* __restrict__ pb) {
    int i = blockIdx.x * blockDim.x + threadIdx.x;
    if (i >= NT) return;
    int r0 = g_rows1[i], r1 = g_rows1[i + 1];
    float s = 0.f;
    int e = r0;
    for (; e + 4 <= r1; e += 4) {
        float s0 = g_trel[g_csr1u[e]];
        float s1 = g_trel[g_csr1u[e + 1]];
        float s2 = g_trel[g_csr1u[e + 2]];
        float s3 = g_trel[g_csr1u[e + 3]];
        s += (s0 + s1) + (s2 + s3);
    }
    for (; e < r1; e++) s += g_trel[g_csr1u[e]];
    g_score[i] = s + g_troot[i] + pb[0];
}

// per-graph bitonic top-410 (desc value, asc index) + fused gate:
// hpb[old] = h2[old]*tanh(score) if kept else 0
__global__ __launch_bounds__(256) void k_topk() {
    __shared__ float sv[512];
    __shared__ int si[512];
    __shared__ float gl[512];
    int g = blockIdx.x, t = threadIdx.x;
    for (int i = t; i < 512; i += 256) { sv[i] = g_score[g * 512 + i]; si[i] = i; }
    __syncthreads();
    for (int k = 2; k <= 512; k <<= 1) {
        for (int j = k >> 1; j > 0; j >>= 1) {
            for (int i = t; i < 512; i += 256) {
                int p = i ^ j;
                if (p > i) {
                    float va = sv[i], vb = sv[p];
                    int ia = si[i], ib = si[p];
                    bool aFirst = (va > vb) || (va == vb && ia < ib);
                    bool up = ((i & k) == 0);
                    if (up != aFirst) { sv[i] = vb; sv[p] = va; si[i] = ib; si[p] = ia; }
                }
            }
            __syncthreads();
        }
    }
    for (int r = t; r < 512; r += 256) {
        int lo = si[r];
        int old = g * 512 + lo;
        if (r < KK) {
            gl[lo] = tanhf(sv[r]);
            g_keptu[old] = 1;
        } else {
            gl[lo] = 0.f;
            g_keptu[old] = 0;
        }
    }
    __syncthreads();
    // gate phase: 512 rows x 128 cols, 8 bf16 per iteration
    for (int idx = t; idx < 512 * 16; idx += 256) {
        int lr = idx >> 4, c = idx & 15;
        float gt = gl[lr];
        size_t off = (size_t)(g * 512 + lr) * 128 + c * 8;
        uint4 v = *(const uint4*)&g_hb2[off];
        uint4 o;
        o.x = (unsigned int)f2b(b2f((unsigned short)(v.x & 0xffff)) * gt) |
              ((unsigned int)f2b(b2f((unsigned short)(v.x >> 16)) * gt) << 16);
        o.y = (unsigned int)f2b(b2f((unsigned short)(v.y & 0xffff)) * gt) |
              ((unsigned int)f2b(b2f((unsigned short)(v.y >> 16)) * gt) << 16);
        o.z = (unsigned int)f2b(b2f((unsigned short)(v.z & 0xffff)) * gt) |
              ((unsigned int)f2b(b2f((unsigned short)(v.z >> 16)) * gt) << 16);
        o.w = (unsigned int)f2b(b2f((unsigned short)(v.w & 0xffff)) * gt) |
              ((unsigned int)f2b(b2f((unsigned short)(v.w >> 16)) * gt) << 16);
        *(uint4*)&g_hpb[off] = o;
    }
}

// ---------------- MLP head + log_softmax ------------------------------------
__global__ __launch_bounds__(128) void k_head(const float* __restrict__ W1, const float* __restrict__ b1,
                                              const float* __restrict__ W2, const float* __restrict__ b2,
                                              float* __restrict__ out) {
    __shared__ float xr[512];
    __shared__ float r0[128], r1[128];
    int g = blockIdx.x, t = threadIdx.x;
    for (int i = t; i < 512; i += 128) {
        int sec = i >> 7, c = i & 127;
        const float* p = &g_xc4[((sec * NB + g) * 4) * 128 + c];
        float v = p[0] + p[128] + p[256] + p[384];
        float inv = (sec < 2) ? (1.0f / 512.0f) : (1.0f / 410.0f);
        xr[i] = v * inv;
    }
    __syncthreads();
    float acc = b1[t];
    for (int k = 0; k < 512; k++) acc += xr[k] * W1[k * 128 + t];
    acc = fmaxf(acc, 0.f);
    r0[t] = acc * W2[t * 2 + 0];
    r1[t] = acc * W2[t * 2 + 1];
    __syncthreads();
    for (int off = 64; off > 0; off >>= 1) {
        if (t < off) { r0[t] += r0[t + off]; r1[t] += r1[t + off]; }
        __syncthreads();
    }
    if (t == 0) {
        float z0 = r0[0] + b2[0], z1 = r1[0] + b2[1];
        float m = fmaxf(z0, z1);
        float l = m + logf(expf(z0 - m) + expf(z1 - m));
        out[g * 2 + 0] = z0 - l;
        out[g * 2 + 1] = z1 - l;
    }
}

// ---------------- launch -----------------------------------------------------
extern "C" void kernel_launch(void* const* d_in, const int* in_sizes, int n_in,
                              void* d_out, int out_size, void* d_ws, size_t ws_size,
                              hipStream_t stream) {
    const float* x = (const float*)d_in[0];
    const int* ei = (const int*)d_in[1];
    const int* src = ei;
    const int* dst = ei + EE;
    const float* W1r = (const float*)d_in[3];
    const float* W1o = (const float*)d_in[4];
    const float* b1 = (const float*)d_in[5];
    const float* Wcr = (const float*)d_in[6];
    const float* Wco = (const float*)d_in[7];
    const float* bc = (const float*)d_in[8];
    const float* pwr = (const float*)d_in[9];
    const float* pwt = (const float*)d_in[10];
    const float* pb = (const float*)d_in[11];
    const float* l1W = (const float*)d_in[12];
    const float* l1b = (const float*)d_in[13];
    const float* l2W = (const float*)d_in[14];
    const float* l2b = (const float*)d_in[15];
    float* out = (float*)d_out;

    // ---- prep (x->bf16, weights->bf16, zero bcnt) ----
    k_prep<<<(1048576 + 16384 + 98304 + 128 + 255) / 256, 256, 0, stream>>>(x, W1r, W1o, Wcr, Wco);

    // ---- CSR1 via counting sort ----
    k_bhist<<<1024, 256, 0, stream>>>(dst);
    k_bscan<<<1, 128, 0, stream>>>();
    k_bscatter<<<1024, 256, 0, stream>>>(src, dst);
    k_bcsr<<<128, 512, 0, stream>>>();

    // ---- conv1: agg64(xb); hb1 = relu([agg|xb]@wt1 + b1); pool -> sec0 ----
    k_agg<64, 0><<<NT / 32, 256, 0, stream>>>(0, 5);
    k_mm<64, 64, 0, 0><<<NT / 128, 256, 0, stream>>>(5, 0, 6, 0, b1, 1, 0, pwr, pwt);

    // ---- conv2 -> hb2; pool -> sec1; score dots fused ----
    k_agg<128, 0><<<NT / 16, 256, 0, stream>>>(1, 3);
    k_mm<128, 128, 0, 1><<<NT / 128, 256, 0, stream>>>(3, 1, 7, 0, bc, 2, 1, pwr, pwt);

    // ---- SAGPool: score agg, per-graph top-410 + gate ----
    k_score_agg<<<NT / 256, 256, 0, stream>>>(pb);
    k_topk<<<NB, 256, 0, stream>>>();

    // ---- conv3 (old-id space, masked) -> hb1; pool -> sec2; store kinv ----
    k_agg<128, 1><<<NT / 16, 256, 0, stream>>>(4, 3);
    k_mm<128, 128, 1, 0><<<NT / 128, 256, 0, stream>>>(3, 4, 7, 32768, bc + 128, 1, 2, pwr, pwt);

    // ---- conv4 -> hb2; pool -> sec3; reuse kinv ----
    k_agg<128, 2><<<NT / 16, 256, 0, stream>>>(1, 3);
    k_mm<128, 128, 1, 0><<<NT / 128, 256, 0, stream>>>(3, 1, 7, 65536, bc + 256, 2, 3, pwr, pwt);

    // ---- head ----
    k_head<<<NB, 128, 0, stream>>>(l1W, l1b, l2W, l2b, out);
}